// Round 9
// baseline (1722.799 us; speedup 1.0000x reference)
//
#include <hip/hip_runtime.h>
#include <stdint.h>

typedef unsigned short u16;
typedef __bf16 bf16x8 __attribute__((ext_vector_type(8)));
typedef float f32x4 __attribute__((ext_vector_type(4)));

#define DEV static __device__ __forceinline__

DEV float bf2f(u16 u) { unsigned v = ((unsigned)u) << 16; float f; __builtin_memcpy(&f, &v, 4); return f; }
DEV u16 f2bf(float f) {
  unsigned x; __builtin_memcpy(&x, &f, 4);
  x += 0x7FFFu + ((x >> 16) & 1u);            // round-to-nearest-even
  return (u16)(x >> 16);
}
DEV float wred_sum(float v) { for (int m = 32; m; m >>= 1) v += __shfl_xor(v, m); return v; }
DEV float wred_max(float v) { for (int m = 32; m; m >>= 1) v = fmaxf(v, __shfl_xor(v, m)); return v; }
DEV void wred_max4(f32x4& v) {
  for (int m = 32; m; m >>= 1) {
#pragma unroll
    for (int i = 0; i < 4; ++i) v[i] = fmaxf(v[i], __shfl_xor(v[i], m));
  }
}
DEV void wred_sum4(f32x4& v) {
  for (int m = 32; m; m >>= 1) {
#pragma unroll
    for (int i = 0; i < 4; ++i) v[i] += __shfl_xor(v[i], m);
  }
}

// ---------------- GEMM: C[M,N] = A[M,K] @ Bt[N,K]^T  (A,Bt bf16; acc f32) ----------------
// head-mode (hA|hB|hC != 0): blockIdx.z = h*nsplit + sp; A/B/ein offset by h, K-range by sp.
// swzn != 0: 1-D grid.x = nrt*swzn, XCD-banded bijective mapping, col-fastest within band
// (same row-tile's col blocks run consecutively on one XCD -> A tile L2-hit, B panel L2-resident).
enum { M_ATOMIC = 0, M_SCALE2, M_BLEND, M_BF16, M_BF16B, M_F32B, M_PART };

template <int MODE>
__global__ __launch_bounds__(256) void k_gemm(
    const u16* __restrict__ A, const u16* __restrict__ B,
    int M, int lda, int ldb, int Ksteps, int kper,
    void* __restrict__ C1v, float* __restrict__ C2, int ldc,
    const float* __restrict__ rowsum, const float* __restrict__ ein, int ldein,
    const float* __restrict__ alphap, const float* __restrict__ bias,
    long hA, long hB, long hC, int nsplit, long hE, int swzn)
{
  __shared__ u16 As[4096], Bs[4096];
  const int tid = threadIdx.x, lane = tid & 63, wid = tid >> 6;
  long m0, n0;
  if (swzn) {
    int total = gridDim.x;
    int x = blockIdx.x & 7, jj = blockIdx.x >> 3;
    int q = total >> 3, rb = total & 7;
    int st = x * q + (x < rb ? x : rb);
    int s = st + jj;
    int rowt = s / swzn;
    m0 = (long)rowt * 128;
    n0 = (long)(s - rowt * swzn) * 128;
  } else {
    m0 = (long)blockIdx.x * 128;
    n0 = (long)blockIdx.y * 128;
  }
  int ks, kend;
  long chead = 0;
  int hz = 0;
  if (hA | hB | hC) {
    int z = blockIdx.z;
    hz = z / nsplit;
    int sp = z - hz * nsplit;
    A += (long)hz * hA;
    B += (long)hz * hB;
    chead = (MODE == M_PART) ? (long)z * hC : (long)hz * hC;
    ks = sp * kper;
    kend = ks + kper; if (kend > Ksteps) kend = Ksteps;
  } else {
    ks = blockIdx.z * kper;
    kend = ks + kper; if (kend > Ksteps) kend = Ksteps;
  }
  if (MODE == M_BLEND) ein += (long)hz * hE;

  const u16 *ag[2], *bg[2];
  u16 *al[2], *bl[2];
#pragma unroll
  for (int i = 0; i < 2; ++i) {
    int s = (wid * 2 + i) * 64 + lane;
    int row = s >> 2, cs = (s & 3) ^ ((row >> 1) & 3);
    ag[i] = A + (m0 + row) * (long)lda + cs * 8;
    bg[i] = B + (n0 + row) * (long)ldb + cs * 8;
    al[i] = As + (wid * 2 + i) * 512;
    bl[i] = Bs + (wid * 2 + i) * 512;
  }
  const int kq = lane >> 4, rr = lane & 15;
  const int wm = wid >> 1, wn = wid & 1;

  f32x4 acc[4][4] = {};

  for (; ks < kend; ++ks) {
    long ko = (long)ks * 32;
#pragma unroll
    for (int i = 0; i < 2; ++i) {
      __builtin_amdgcn_global_load_lds((const __attribute__((address_space(1))) unsigned int*)(ag[i] + ko),
                                       (__attribute__((address_space(3))) unsigned int*)al[i], 16, 0, 0);
      __builtin_amdgcn_global_load_lds((const __attribute__((address_space(1))) unsigned int*)(bg[i] + ko),
                                       (__attribute__((address_space(3))) unsigned int*)bl[i], 16, 0, 0);
    }
    __syncthreads();
    bf16x8 af[4], bff[4];
#pragma unroll
    for (int i = 0; i < 4; ++i) {
      int ra = wm * 64 + i * 16 + rr, ca = kq ^ ((ra >> 1) & 3);
      af[i] = *(const bf16x8*)(As + ra * 32 + ca * 8);
      int rb = wn * 64 + i * 16 + rr, cb = kq ^ ((rb >> 1) & 3);
      bff[i] = *(const bf16x8*)(Bs + rb * 32 + cb * 8);
    }
#pragma unroll
    for (int i = 0; i < 4; ++i)
#pragma unroll
      for (int j = 0; j < 4; ++j)
        acc[i][j] = __builtin_amdgcn_mfma_f32_16x16x32_bf16(af[i], bff[j], acc[i][j], 0, 0, 0);
    __syncthreads();
  }

  float* Cf = (float*)C1v;
  u16* Cu = (u16*)C1v;
  const int r4 = (lane >> 4) << 2;
#pragma unroll
  for (int i = 0; i < 4; ++i) {
#pragma unroll
    for (int rg = 0; rg < 4; ++rg) {
      long row = m0 + wm * 64 + i * 16 + r4 + rg;
      if (row >= M) continue;
      float scale = 0.f, al_ = 0.f, ml_ = 0.f;
      if (MODE == M_SCALE2) scale = 1.f / (rowsum[(long)hz * M + row] + 1e-5f);
      if (MODE == M_BLEND) { al_ = *alphap; ml_ = 1.f - al_; }
#pragma unroll
      for (int j = 0; j < 4; ++j) {
        long col = n0 + wn * 64 + j * 16 + rr;
        float v = acc[i][j][rg];
        long idx = chead + row * (long)ldc + col;
        if (MODE == M_ATOMIC) atomicAdd(Cf + idx, v);
        else if (MODE == M_PART) Cf[idx] = v;
        else if (MODE == M_SCALE2) { float sv = v * scale; Cf[idx] = sv; C2[idx] = sv; }
        else if (MODE == M_BLEND) { float e = ein[row * (long)ldein + col]; Cf[idx] = fmaxf(al_ * v + ml_ * e, 0.f); }
        else if (MODE == M_BF16) Cu[idx] = f2bf(v);
        else if (MODE == M_BF16B) Cu[idx] = f2bf(v + bias[col]);
        else if (MODE == M_F32B) Cf[idx] = v + bias[col];
      }
    }
  }
}

// ---------------- converters ----------------
__global__ void k_cvt(const float* __restrict__ in, u16* __restrict__ out, long R, long C, long Cp, long ostride)
{
  long idx = (long)blockIdx.x * blockDim.x + threadIdx.x;
  long cw = Cp >> 3;
  if (idx >= R * cw) return;
  long r = idx / cw, c8 = (idx % cw) << 3;
  u16 tmp[8];
  if (c8 < C) {
    const f32x4* p = (const f32x4*)(in + r * C + c8);
    f32x4 a = p[0], b = p[1];
#pragma unroll
    for (int i = 0; i < 4; ++i) { tmp[i] = f2bf(a[i]); tmp[4 + i] = f2bf(b[i]); }
  } else {
#pragma unroll
    for (int i = 0; i < 8; ++i) tmp[i] = 0;
  }
  uint4 w_; __builtin_memcpy(&w_, tmp, 16);
  *(uint4*)(out + r * ostride + c8) = w_;
}

__global__ __launch_bounds__(256) void k_cvtT(const float* __restrict__ in, u16* __restrict__ out,
                                              int Bh, int R, int C, int Rp)
{
  __shared__ float tile[64][65];
  int bid = blockIdx.x;
  int nrt = Rp >> 6;
  int rt = bid % nrt; bid /= nrt;
  int nct = C >> 6;
  int ct = bid % nct; int b = bid / nct;
  int t = threadIdx.x;
  int tr = t >> 4, tc4 = (t & 15) << 2;
#pragma unroll
  for (int i = 0; i < 4; ++i) {
    int r = (rt << 6) + tr + i * 16;
    f32x4 v = {0.f, 0.f, 0.f, 0.f};
    if (r < R) v = *(const f32x4*)(in + ((long)b * R + r) * C + (ct << 6) + tc4);
    tile[tr + i * 16][tc4 + 0] = v[0];
    tile[tr + i * 16][tc4 + 1] = v[1];
    tile[tr + i * 16][tc4 + 2] = v[2];
    tile[tr + i * 16][tc4 + 3] = v[3];
  }
  __syncthreads();
  int wc = t >> 4, wr4 = (t & 15) << 2;
#pragma unroll
  for (int i = 0; i < 4; ++i) {
    int c = wc + i * 16;
    u16 o[4];
#pragma unroll
    for (int k2 = 0; k2 < 4; ++k2) o[k2] = f2bf(tile[wr4 + k2][c]);
    unsigned long long pk; __builtin_memcpy(&pk, o, 8);
    *(unsigned long long*)(out + ((long)b * C + (ct << 6) + c) * Rp + (rt << 6) + wr4) = pk;
  }
}

// 4 adjacency planes: f32 [N][C] -> bf16 planes + per-plane rowsum
__global__ __launch_bounds__(256) void k_adj4(const float* __restrict__ a0, const float* __restrict__ a1,
                                              const float* __restrict__ a2, const float* __restrict__ a3,
                                              u16* __restrict__ o01, u16* __restrict__ o23,
                                              float* __restrict__ rowsum, int C, int Cp, int N)
{
  int r = blockIdx.x, pl = blockIdx.y, t = threadIdx.x;
  const float* in = pl == 0 ? a0 : pl == 1 ? a1 : pl == 2 ? a2 : a3;
  u16* out = pl < 2 ? o01 + (size_t)pl * N * Cp : o23 + (size_t)(pl - 2) * N * Cp;
  f32x4 v = {0.f, 0.f, 0.f, 0.f};
  int c = t << 2;
  if (c + 3 < C) v = *(const f32x4*)(in + (long)r * C + c);
  u16 o[4];
#pragma unroll
  for (int i = 0; i < 4; ++i) o[i] = f2bf(v[i]);
  unsigned long long pk; __builtin_memcpy(&pk, o, 8);
  *(unsigned long long*)(out + (long)r * Cp + c) = pk;
  float s = wred_sum(v[0] + v[1] + v[2] + v[3]);
  __shared__ float ws4[4];
  if ((t & 63) == 0) ws4[t >> 6] = s;
  __syncthreads();
  if (t == 0) rowsum[(long)pl * N + r] = ws4[0] + ws4[1] + ws4[2] + ws4[3];
}

// reduce NS partial planes: o[h][i] = sum_sp P[h*NS+sp][i], plane = 32768 f32
__global__ void k_red(const float* __restrict__ P, float* __restrict__ o, int NS)
{
  int i = blockIdx.x * 256 + threadIdx.x;         // 0..65535
  int h = i >> 15, rem = i & 32767;
  const float* p = P + (long)h * NS * 32768 + rem;
  float s = 0.f;
  for (int k = 0; k < NS; ++k) s += p[(long)k * 32768];
  o[i] = s;
}

// ---------------- CSR build ----------------
__global__ void k_zero_i(int* p, int n) { for (int i = blockIdx.x * blockDim.x + threadIdx.x; i < n; i += gridDim.x * blockDim.x) p[i] = 0; }
__global__ void k_copy_i(const int* __restrict__ a, int* __restrict__ b, int n) { for (int i = blockIdx.x * blockDim.x + threadIdx.x; i < n; i += gridDim.x * blockDim.x) b[i] = a[i]; }
__global__ void k_hist(const int* __restrict__ dst, int* __restrict__ deg, int E)
{ for (int i = blockIdx.x * blockDim.x + threadIdx.x; i < E; i += gridDim.x * blockDim.x) atomicAdd(&deg[dst[i]], 1); }
__global__ void k_scatter(const int* __restrict__ src, const int* __restrict__ dst, int* __restrict__ cur,
                          int* __restrict__ srcs, int E)
{
  for (int i = blockIdx.x * blockDim.x + threadIdx.x; i < E; i += gridDim.x * blockDim.x) {
    int p = atomicAdd(&cur[dst[i]], 1);
    srcs[p] = src[i];
  }
}
// single-block scan: per-thread serial chunk + LDS scan + serial writeback
__global__ __launch_bounds__(1024) void k_scan(const int* __restrict__ deg, int* __restrict__ off, int n)
{
  __shared__ int bsum[1024];
  int t = threadIdx.x;
  int per = (n + 1023) >> 10;
  int s0 = t * per, s1 = s0 + per; if (s1 > n) s1 = n;
  int s = 0;
  for (int i = s0; i < s1; ++i) s += deg[i];
  bsum[t] = s;
  __syncthreads();
  for (int d = 1; d < 1024; d <<= 1) {
    int x = (t >= d) ? bsum[t - d] : 0;
    __syncthreads();
    bsum[t] += x;
    __syncthreads();
  }
  if (t == 0) off[0] = 0;
  int run = t ? bsum[t - 1] : 0;
  for (int i = s0; i < s1; ++i) { run += deg[i]; off[i + 1] = run; }
}

// ---------------- GAT ----------------
// es/ed dots + fused int8 row quantization; q8 layout is DIM-MAJOR: row byte = d*4 + hd
__global__ __launch_bounds__(256) void k_esed(const u16* __restrict__ h, const float* __restrict__ as_,
                                              const float* __restrict__ ad_, float* __restrict__ esq,
                                              float* __restrict__ ed, signed char* __restrict__ q8, int N)
{
  __shared__ int stg[4][64];
  int n = blockIdx.x, t = threadIdx.x, hd = t >> 6, l = t & 63;
  long base = (long)n * 1024 + hd * 256 + (l << 2);
  ushort4 hv = *(const ushort4*)(h + base);
  float h0 = bf2f(hv.x), h1 = bf2f(hv.y), h2 = bf2f(hv.z), h3 = bf2f(hv.w);
  const float* ap = as_ + hd * 256 + (l << 2);
  const float* dp = ad_ + hd * 256 + (l << 2);
  float ps = h0 * ap[0] + h1 * ap[1] + h2 * ap[2] + h3 * ap[3];
  float pd = h0 * dp[0] + h1 * dp[1] + h2 * dp[2] + h3 * dp[3];
  ps = wred_sum(ps); pd = wred_sum(pd);
  float amax = fmaxf(fmaxf(fabsf(h0), fabsf(h1)), fmaxf(fabsf(h2), fabsf(h3)));
  amax = wred_max(amax);
  float rsc = amax > 0.f ? 127.f / amax : 0.f;
  signed char qb[4];
  qb[0] = (signed char)__float2int_rn(h0 * rsc);
  qb[1] = (signed char)__float2int_rn(h1 * rsc);
  qb[2] = (signed char)__float2int_rn(h2 * rsc);
  qb[3] = (signed char)__float2int_rn(h3 * rsc);
  int qw; __builtin_memcpy(&qw, qb, 4);
  stg[hd][l] = qw;
  if (l == 0) {
    esq[n * 8 + hd] = ps;
    esq[n * 8 + 4 + hd] = amax * (1.f / 127.f);
    ed[n * 4 + hd] = pd;
  }
  __syncthreads();
  if (t < 64) {
    int b0 = stg[0][t], b1 = stg[1][t], b2 = stg[2][t], b3 = stg[3][t];
    unsigned r[4];
#pragma unroll
    for (int i = 0; i < 4; ++i) {
      int sh = 8 * i;
      r[i] = ((unsigned)((b0 >> sh) & 0xff)) | ((unsigned)((b1 >> sh) & 0xff) << 8) |
             ((unsigned)((b2 >> sh) & 0xff) << 16) | ((unsigned)((b3 >> sh) & 0xff) << 24);
    }
    uint4 o; __builtin_memcpy(&o, r, 16);
    *(uint4*)(q8 + (long)n * 1024 + (t << 4)) = o;
  }
}

// persistent wave-per-node softmax aggregation; dim-major int8 gather;
// LDS broadcast of (weights, src). grid (1024, 2 sides), wave-strided node loop.
__global__ __launch_bounds__(256) void k_gat(const signed char* __restrict__ q8,
                                             const float* __restrict__ esq, const float* __restrict__ ed,
                                             const int* __restrict__ off0, const int* __restrict__ srcs0,
                                             const int* __restrict__ off1, const int* __restrict__ srcs1,
                                             u16* __restrict__ x0, u16* __restrict__ x1, int N, int NPq)
{
  __shared__ f32x4 sw[4][64];
  __shared__ int ss[4][64];
  int t = threadIdx.x, w = t >> 6, l = t & 63;
  int side = blockIdx.y;
  const int* off = side ? off1 : off0;
  const int* srcs = side ? srcs1 : srcs0;
  u16* xout = side ? x1 : x0;
  size_t ofs = side ? (size_t)NPq : 0;
  q8 += ofs * 1024; esq += ofs * 8;
  const long loff = l << 2;
  const int nstride = gridDim.x * 4;

  for (int n = blockIdx.x * 4 + w; n < N; n += nstride) {
    int e0 = off[n], deg = off[n + 1] - e0;
    f32x4 edv = *(const f32x4*)(ed + (ofs + n) * 4);

    f32x4 m = {-1e30f, -1e30f, -1e30f, -1e30f};
    f32x4 psum = {0.f, 0.f, 0.f, 0.f};
    f32x4 acc0 = {0.f, 0.f, 0.f, 0.f};
    f32x4 acc1 = {0.f, 0.f, 0.f, 0.f};
    f32x4 acc2 = {0.f, 0.f, 0.f, 0.f};
    f32x4 acc3 = {0.f, 0.f, 0.f, 0.f};

    for (int base = 0; base < deg; base += 64) {
      int cnt = min(64, deg - base);
      bool act = l < cnt;
      int s = 0;
      f32x4 v = {-1e30f, -1e30f, -1e30f, -1e30f};
      if (act) {
        s = srcs[e0 + base + l];
        f32x4 es4 = *(const f32x4*)(esq + (long)s * 8);
#pragma unroll
        for (int hd = 0; hd < 4; ++hd) {
          float x = es4[hd] + edv[hd];
          v[hd] = x >= 0.f ? x : 0.2f * x;
        }
      }
      f32x4 mc = v;
      wred_max4(mc);
      f32x4 nm;
#pragma unroll
      for (int hd = 0; hd < 4; ++hd) nm[hd] = fmaxf(m[hd], mc[hd]);
      f32x4 sc;
#pragma unroll
      for (int hd = 0; hd < 4; ++hd) sc[hd] = __expf(m[hd] - nm[hd]);
      psum *= sc;
      acc0 *= sc[0]; acc1 *= sc[1]; acc2 *= sc[2]; acc3 *= sc[3];
      m = nm;
      f32x4 wq4 = {0.f, 0.f, 0.f, 0.f};
      if (act) {
        f32x4 qs4 = *(const f32x4*)(esq + (long)s * 8 + 4);
#pragma unroll
        for (int hd = 0; hd < 4; ++hd) {
          float e = __expf(v[hd] - m[hd]);
          psum[hd] += e;
          wq4[hd] = e * qs4[hd];
        }
      }
      sw[w][l] = wq4;
      ss[w][l] = s;
#pragma unroll 4
      for (int j = 0; j < cnt; ++j) {
        f32x4 w4 = sw[w][j];
        int sj = ss[w][j];
        uint4 c = *(const uint4*)(q8 + (long)sj * 1024 + (l << 4));
        const int* cw = (const int*)&c;
#pragma unroll
        for (int i = 0; i < 4; ++i) {
          int ci = cw[i];
          acc0[i] += w4[0] * (float)((signed char)(ci));
          acc1[i] += w4[1] * (float)((signed char)(ci >> 8));
          acc2[i] += w4[2] * (float)((signed char)(ci >> 16));
          acc3[i] += w4[3] * (float)(ci >> 24);
        }
      }
    }
    wred_sum4(psum);
    f32x4 rd;
#pragma unroll
    for (int hd = 0; hd < 4; ++hd) rd[hd] = 1.f / (psum[hd] + 1e-16f);
    float mean[4]; float nrm = 0.f;
#pragma unroll
    for (int i = 0; i < 4; ++i) {
      float y0 = acc0[i] * rd[0]; y0 = y0 > 0.f ? y0 : __expf(y0) - 1.f;
      float y1 = acc1[i] * rd[1]; y1 = y1 > 0.f ? y1 : __expf(y1) - 1.f;
      float y2 = acc2[i] * rd[2]; y2 = y2 > 0.f ? y2 : __expf(y2) - 1.f;
      float y3 = acc3[i] * rd[3]; y3 = y3 > 0.f ? y3 : __expf(y3) - 1.f;
      float mv = 0.25f * (y0 + y1 + y2 + y3);
      mean[i] = mv; nrm += mv * mv;
    }
    nrm = wred_sum(nrm);
    float scn = 1.f / fmaxf(sqrtf(nrm), 1e-12f);
    u16 o[4];
#pragma unroll
    for (int i = 0; i < 4; ++i) o[i] = f2bf(mean[i] * scn);
    unsigned long long pk; __builtin_memcpy(&pk, o, 8);
    *(unsigned long long*)(xout + (long)n * 768 + loff) = pk;
  }
}

// ---------------- MHA (folded) ----------------
__global__ void k_bias2(const float* __restrict__ wq, const float* __restrict__ wk,
                        const float* __restrict__ fcw,
                        const float* __restrict__ bq, const float* __restrict__ bk,
                        const float* __restrict__ bv,
                        float* __restrict__ vq1, float* __restrict__ vq2,
                        float* __restrict__ beff2, float* __restrict__ s3)
{
  int t = blockIdx.x * 256 + threadIdx.x;   // 0..1023
  int h = t >> 8, d = t & 255;
  float a1 = 0.f, a2 = 0.f, a3 = 0.f;
  for (int j = 0; j < 256; ++j) {
    a1 += wk[(long)d * 1024 + h * 256 + j] * bq[h * 256 + j];
    a2 += wq[(long)d * 1024 + h * 256 + j] * bk[h * 256 + j];
    a3 += bv[h * 256 + j] * fcw[(long)(h * 256 + j) * 256 + d];
  }
  vq1[t] = a1; vq2[t] = a2; beff2[t] = a3;
  if (d == 0) {
    float s = 0.f;
    for (int j = 0; j < 256; ++j) s += bq[h * 256 + j] * bk[h * 256 + j];
    s3[h] = s;
  }
}

// per-node scores; grid (N, 2 sides)
__global__ __launch_bounds__(256) void k_score2(const u16* __restrict__ x, const u16* __restrict__ kg,
                                                const float* __restrict__ vq1, const float* __restrict__ vq2,
                                                const float* __restrict__ s3, float* __restrict__ attn,
                                                int N, int NPq)
{
  int n = blockIdx.x, side = blockIdx.y, t = threadIdx.x, hd = t >> 6, l = t & 63;
  long rbase = (long)side * 3 * NPq + (long)n * 3;
  int i4 = l << 2;
  f32x4 xr[3], kc[3];
#pragma unroll
  for (int r = 0; r < 3; ++r) {
    ushort4 a = *(const ushort4*)(x + (rbase + r) * 256 + i4);
    xr[r][0] = bf2f(a.x); xr[r][1] = bf2f(a.y); xr[r][2] = bf2f(a.z); xr[r][3] = bf2f(a.w);
    ushort4 b = *(const ushort4*)(kg + (rbase + r) * 1024 + hd * 256 + i4);
    kc[r][0] = bf2f(b.x); kc[r][1] = bf2f(b.y); kc[r][2] = bf2f(b.z); kc[r][3] = bf2f(b.w);
  }
  f32x4 v1 = *(const f32x4*)(vq1 + hd * 256 + i4);
  f32x4 v2 = *(const f32x4*)(vq2 + hd * 256 + i4);
  float red[15];
#pragma unroll
  for (int r = 0; r < 3; ++r)
#pragma unroll
    for (int c = 0; c < 3; ++c) {
      f32x4 p = xr[r] * kc[c];
      red[r * 3 + c] = p[0] + p[1] + p[2] + p[3];
    }
#pragma unroll
  for (int c = 0; c < 3; ++c) {
    f32x4 p1 = xr[c] * v1;
    f32x4 p2 = xr[c] * v2;
    red[9 + c] = p1[0] + p1[1] + p1[2] + p1[3];
    red[12 + c] = p2[0] + p2[1] + p2[2] + p2[3];
  }
#pragma unroll
  for (int i = 0; i < 15; ++i) red[i] = wred_sum(red[i]);
  if (l == 0) {
    float s3h = s3[hd];
    float* out = attn + ((long)side * N + n) * 36 + hd * 9;
#pragma unroll
    for (int r = 0; r < 3; ++r) {
      float v0 = (red[r * 3 + 0] + red[9 + 0] + red[12 + r] + s3h) * 0.0625f;
      float v1_ = (red[r * 3 + 1] + red[9 + 1] + red[12 + r] + s3h) * 0.0625f;
      float v2_ = (red[r * 3 + 2] + red[9 + 2] + red[12 + r] + s3h) * 0.0625f;
      float mm = fmaxf(v0, fmaxf(v1_, v2_));
      float e0 = __expf(v0 - mm), e1 = __expf(v1_ - mm), e2 = __expf(v2_ - mm);
      float rs = 1.f / (e0 + e1 + e2);
      out[r * 3 + 0] = e0 * rs; out[r * 3 + 1] = e1 * rs; out[r * 3 + 2] = e2 * rs;
    }
  }
}

// fused combine + fc-bias + residual + LayerNorm + range-mean; grid (N, 2 sides)
__global__ __launch_bounds__(256) void k_cln(const u16* __restrict__ vf, const float* __restrict__ attn,
                                             const u16* __restrict__ x, const float* __restrict__ fcb,
                                             const float* __restrict__ g, const float* __restrict__ b,
                                             float* __restrict__ out0, float* __restrict__ out1,
                                             int N, int NPq)
{
  int n = blockIdx.x, side = blockIdx.y, t = threadIdx.x, w = t >> 6, l = t & 63;
  long rbase = (long)side * 3 * NPq + (long)n * 3;
  float* out = (side ? out1 : out0) + (long)n * 768;
  __shared__ float aa[36];
  __shared__ float ybuf[3][256];
  if (t < 36) aa[t] = attn[((long)side * N + n) * 36 + t];
  __syncthreads();
  if (w < 3) {
    int d4 = l << 2;
    f32x4 acc = {0.f, 0.f, 0.f, 0.f};
#pragma unroll
    for (int h = 0; h < 4; ++h)
#pragma unroll
      for (int rp = 0; rp < 3; ++rp) {
        float wgt = aa[h * 9 + w * 3 + rp];
        ushort4 vv = *(const ushort4*)(vf + (rbase + rp) * 1024 + h * 256 + d4);
        acc[0] += wgt * bf2f(vv.x); acc[1] += wgt * bf2f(vv.y);
        acc[2] += wgt * bf2f(vv.z); acc[3] += wgt * bf2f(vv.w);
      }
    f32x4 fb = *(const f32x4*)(fcb + d4);
    ushort4 xu = *(const ushort4*)(x + (rbase + w) * 256 + d4);
    acc[0] += fb[0] + bf2f(xu.x); acc[1] += fb[1] + bf2f(xu.y);
    acc[2] += fb[2] + bf2f(xu.z); acc[3] += fb[3] + bf2f(xu.w);
    float s1 = acc[0] + acc[1] + acc[2] + acc[3];
    float s2 = acc[0] * acc[0] + acc[1] * acc[1] + acc[2] * acc[2] + acc[3] * acc[3];
    s1 = wred_sum(s1); s2 = wred_sum(s2);
    float mu = s1 * 0.00390625f;
    float var = s2 * 0.00390625f - mu * mu;
    float rs = rsqrtf(var + 1e-5f);
#pragma unroll
    for (int i = 0; i < 4; ++i) {
      int d = d4 + i;
      ybuf[w][d] = (acc[i] - mu) * rs * g[d] + b[d];
    }
  }
  __syncthreads();
  if (t < 64) {
#pragma unroll
    for (int i = 0; i < 4; ++i) {
      int d = (t << 2) + i;
      out[d] = (ybuf[0][d] + ybuf[1][d] + ybuf[2][d]) * (1.f / 3.f);
    }
  }
}

// aug = e + ent, both sides; out2/out3 contiguous
__global__ void k_aug(const float* __restrict__ e, const float* __restrict__ ent0,
                      const float* __restrict__ ent1, float* __restrict__ out, int N)
{
  long i = (long)blockIdx.x * blockDim.x + threadIdx.x;
  if (i >= (long)N * 128) return;
  int side = i >= (long)N * 64;
  long ii = side ? i - (long)N * 64 : i;
  const float* ent = side ? ent1 : ent0;
  long n = ii >> 6; int d4 = (int)(ii & 63) << 2;
  f32x4 a = *(const f32x4*)(e + ((long)side * N + n) * 256 + d4);
  f32x4 c = *(const f32x4*)(ent + n * 256 + d4);
  *(f32x4*)(out + ((long)side * N + n) * 768 + d4) = a + c;
}

// ---------------- host ----------------
extern "C" void kernel_launch(void* const* d_in, const int* in_sizes, int n_in,
                              void* d_out, int out_size, void* d_ws, size_t ws_size,
                              hipStream_t stream)
{
  (void)n_in; (void)out_size; (void)ws_size;
  const int N = 20000, NP = 20096, RNUM = 1000, RP = 1024;
  const int NT2 = NP + N;
  const int NS = 64;
  const int Es = in_sizes[26] / 2, Et = in_sizes[27] / 2;

  const float* ent_sr = (const float*)d_in[0];
  const float* ent_tg = (const float*)d_in[1];
  const float* rel_in[2] = {(const float*)d_in[2], (const float*)d_in[3]};
  const float* alphap = (const float*)d_in[4];
  const float* ums[2] = {(const float*)d_in[5], (const float*)d_in[7]};
  const float* vt[2]  = {(const float*)d_in[6], (const float*)d_in[8]};
  const float* adj[4] = {(const float*)d_in[9], (const float*)d_in[10], (const float*)d_in[11], (const float*)d_in[12]};
  const float* gat_W  = (const float*)d_in[13];
  const float* gat_as = (const float*)d_in[14];
  const float* gat_ad = (const float*)d_in[15];
  const float* wq = (const float*)d_in[16]; const float* bq = (const float*)d_in[17];
  const float* wk = (const float*)d_in[18]; const float* bk = (const float*)d_in[19];
  const float* wv = (const float*)d_in[20]; const float* bv = (const float*)d_in[21];
  const float* fcw = (const float*)d_in[22]; const float* fcb = (const float*)d_in[23];
  const float* lng = (const float*)d_in[24]; const float* lnb = (const float*)d_in[25];
  const int* edges[2] = {(const int*)d_in[26], (const int*)d_in[27]};
  const int Ecnt[2] = {Es, Et};

  float* out0 = (float*)d_out;
  float* out1 = out0 + (size_t)N * 768;
  float* out2 = out1 + (size_t)N * 768;
  float* out3 = out2 + (size_t)N * 768;

  char* wsp = (char*)d_ws; size_t wo = 0;
  auto alloc = [&](size_t bytes) { void* p = wsp + wo; wo = (wo + bytes + 255) & ~(size_t)255; return p; };

  u16* A_sr = (u16*)alloc((size_t)NP * 768 * 2);
  u16* A_tg = (u16*)alloc((size_t)NP * 768 * 2);     // contiguous after A_sr (size % 256 == 0)
  u16* QBUF = (u16*)alloc((size_t)3 * NT2 * 1024 * 2);  // 246 MB: rel adj 0/1, GAT h, vf
  u16* KBUF = (u16*)alloc((size_t)3 * NT2 * 1024 * 2);  // 246 MB: rel adj 2/3, SVD scratch, q8, kg
  float* PART = (float*)alloc((size_t)2 * NS * 32768 * 4);
  float* rowsum = (float*)alloc((size_t)4 * N * 4);
  u16* relT[2] = {(u16*)alloc(256 * RP * 2), (u16*)alloc(256 * RP * 2)};
  u16* WtG = (u16*)alloc((size_t)2 * 1024 * 256 * 2);
  u16* fcT = (u16*)alloc(256 * 1024 * 2);
  u16* wqB = (u16*)alloc(256 * 1024 * 2);
  u16* wkB = (u16*)alloc(256 * 1024 * 2);
  u16* wvB = (u16*)alloc(256 * 1024 * 2);
  u16* gT  = (u16*)alloc((size_t)4 * 256 * 256 * 2);
  u16* vfT = (u16*)alloc((size_t)4 * 256 * 256 * 2);
  float* vq1 = (float*)alloc(1024 * 4);
  float* vq2 = (float*)alloc(1024 * 4);
  float* beff2 = (float*)alloc(1024 * 4);
  float* s3b = (float*)alloc(4 * 4);
  float* esqb = (float*)alloc((size_t)NT2 * 8 * 4);
  float* edb = (float*)alloc((size_t)NT2 * 4 * 4);
  float* attn = (float*)alloc((size_t)2 * N * 36 * 4);
  int* off_[2]; int* cur_[2]; int* srcs_[2];
  for (int s = 0; s < 2; ++s) {
    off_[s] = (int*)alloc((size_t)(N + 4) * 4);
    cur_[s] = (int*)alloc((size_t)(N + 4) * 4);
    srcs_[s] = (int*)alloc((size_t)Ecnt[s] * 4);
  }
  float* tT2 = (float*)alloc((size_t)2 * 256 * 128 * 4);
  u16* tTb2 = (u16*)alloc((size_t)2 * 256 * 128 * 2);

  // aliases
  u16* hbuf = QBUF;                 // GAT phase
  u16* vfbuf = QBUF;                // MHA phase
  u16* adjbQ = QBUF;                // rel planes 0,1
  u16* adjbK = KBUF;                // rel planes 2,3
  float* e_b = (float*)KBUF;        // SVD: [2][N][256] f32
  u16* eT = (u16*)(e_b + (size_t)2 * N * 256);   // [2][256][NP]
  u16* vtb0 = eT + (size_t)2 * 256 * NP;         // [2][128][NP]
  u16* umb0 = vtb0 + (size_t)2 * 128 * NP;       // [2][NP][128] (rows 0..N used)
  signed char* q8buf = (signed char*)KBUF;       // GAT phase (dim-major int8)
  u16* kgbuf = KBUF;                             // MHA phase

  const float* ent_s[2] = {ent_sr, ent_tg};

  auto cvt = [&](const float* in, u16* out, long R, long C, long Cp, long ostr) {
    long total = R * (Cp >> 3);
    int blocks = (int)((total + 255) / 256);
    k_cvt<<<blocks, 256, 0, stream>>>(in, out, R, C, Cp, ostr);
  };
  auto cvtT = [&](const float* in, u16* out, int Bh, int R, int C, int Rp) {
    int blocks = (Rp >> 6) * (C >> 6) * Bh;
    k_cvtT<<<blocks, 256, 0, stream>>>(in, out, Bh, R, C, Rp);
  };
  auto gemm = [&](int mode, const u16* A, const u16* B, int M, int lda, int ldb, int Kp, int Nt,
                  int zdim, int nsplit,
                  void* C1, float* C2, int ldc, const float* rs, const float* ein, int ldein,
                  const float* alp, const float* bias,
                  long hA = 0, long hB = 0, long hC = 0, long hE = 0, int swz = 0) {
    int Ks = Kp >> 5;
    bool hmode = (hA | hB | hC) != 0;
    int kper = hmode ? (Ks + nsplit - 1) / nsplit
                     : (zdim > 1 ? (Ks + zdim - 1) / zdim : Ks);
    int nrt = (M + 127) >> 7;
    dim3 g(nrt, Nt, zdim);
    int swzn = 0;
    if (swz && !hmode && zdim == 1) { g = dim3(nrt * Nt, 1, 1); swzn = Nt; }
    switch (mode) {
      case M_ATOMIC: k_gemm<M_ATOMIC><<<g, 256, 0, stream>>>(A, B, M, lda, ldb, Ks, kper, C1, C2, ldc, rs, ein, ldein, alp, bias, hA, hB, hC, nsplit, hE, swzn); break;
      case M_SCALE2: k_gemm<M_SCALE2><<<g, 256, 0, stream>>>(A, B, M, lda, ldb, Ks, kper, C1, C2, ldc, rs, ein, ldein, alp, bias, hA, hB, hC, nsplit, hE, swzn); break;
      case M_BLEND:  k_gemm<M_BLEND><<<g, 256, 0, stream>>>(A, B, M, lda, ldb, Ks, kper, C1, C2, ldc, rs, ein, ldein, alp, bias, hA, hB, hC, nsplit, hE, swzn); break;
      case M_BF16:   k_gemm<M_BF16><<<g, 256, 0, stream>>>(A, B, M, lda, ldb, Ks, kper, C1, C2, ldc, rs, ein, ldein, alp, bias, hA, hB, hC, nsplit, hE, swzn); break;
      case M_BF16B:  k_gemm<M_BF16B><<<g, 256, 0, stream>>>(A, B, M, lda, ldb, Ks, kper, C1, C2, ldc, rs, ein, ldein, alp, bias, hA, hB, hC, nsplit, hE, swzn); break;
      case M_F32B:   k_gemm<M_F32B><<<g, 256, 0, stream>>>(A, B, M, lda, ldb, Ks, kper, C1, C2, ldc, rs, ein, ldein, alp, bias, hA, hB, hC, nsplit, hE, swzn); break;
      case M_PART:   k_gemm<M_PART><<<g, 256, 0, stream>>>(A, B, M, lda, ldb, Ks, kper, C1, C2, ldc, rs, ein, ldein, alp, bias, hA, hB, hC, nsplit, hE, swzn); break;
    }
  };

  // ---- CSR build (per side) ----
  for (int s = 0; s < 2; ++s) {
    k_zero_i<<<80, 256, 0, stream>>>(cur_[s], N);
    k_hist<<<1024, 256, 0, stream>>>(edges[s] + Ecnt[s], cur_[s], Ecnt[s]);
    k_scan<<<1, 1024, 0, stream>>>(cur_[s], off_[s], N);
    k_copy_i<<<80, 256, 0, stream>>>(off_[s], cur_[s], N);
    k_scatter<<<1024, 256, 0, stream>>>(edges[s], edges[s] + Ecnt[s], cur_[s], srcs_[s], Ecnt[s]);
  }

  // ---- Relation aggregator: one adj pass + two head-mode GEMMs ----
  cvtT(rel_in[0], relT[0], 1, RNUM, 256, RP);
  cvtT(rel_in[1], relT[1], 1, RNUM, 256, RP);
  {
    dim3 ga(N, 4);
    k_adj4<<<ga, 256, 0, stream>>>(adj[0], adj[1], adj[2], adj[3], adjbQ, adjbK, rowsum, RNUM, RP, N);
  }
  gemm(M_SCALE2, adjbQ, relT[0], N, RP, RP, RP, 2, 2, 1,
       out0 + 256, out2 + 256, 768, rowsum, nullptr, 0, nullptr, nullptr,
       (long)N * RP, 0, 256);
  gemm(M_SCALE2, adjbK, relT[1], N, RP, RP, RP, 2, 2, 1,
       out1 + 256, out3 + 256, 768, rowsum + 2 * N, nullptr, 0, nullptr, nullptr,
       (long)N * RP, 0, 256);

  // ---- SVD global-structure propagation (sides merged per layer) ----
  cvt(vt[0], vtb0, 128, N, NP, NP);
  cvt(vt[1], vtb0 + (size_t)128 * NP, 128, N, NP, NP);
  cvt(ums[0], umb0, N, 128, 128, 128);
  cvt(ums[1], umb0 + (size_t)NP * 128, N, 128, 128, 128);
  for (int l = 0; l < 2; ++l) {
    if (l == 0) {
      cvtT(ent_sr, eT, 1, N, 256, NP);
      cvtT(ent_tg, eT + (size_t)256 * NP, 1, N, 256, NP);
    } else {
      cvtT(e_b, eT, 2, N, 256, NP);
    }
    gemm(M_PART, eT, vtb0, 256, NP, NP, NP, 1, 2 * NS, NS,
         PART, nullptr, 128, nullptr, nullptr, 0, nullptr, nullptr,
         (long)256 * NP, (long)128 * NP, 32768);
    k_red<<<256, 256, 0, stream>>>(PART, tT2, NS);
    cvt(tT2, tTb2, 512, 128, 128, 128);
    if (l == 0) {
      for (int s = 0; s < 2; ++s)
        gemm(M_BLEND, umb0 + (size_t)s * NP * 128, tTb2 + (size_t)s * 32768, N, 128, 128, 128, 2, 1, 1,
             e_b + (size_t)s * N * 256, nullptr, 256, nullptr, ent_s[s], 256, alphap, nullptr,
             0, 0, 0, 0, 1);
    } else {
      gemm(M_BLEND, umb0, tTb2, N, 128, 128, 128, 2, 2, 1,
           e_b, nullptr, 256, nullptr, e_b, 256, alphap, nullptr,
           (long)NP * 128, 32768, (long)N * 256, (long)N * 256);
    }
  }
  k_aug<<<(int)(((long)N * 128 + 255) / 256), 256, 0, stream>>>(e_b, ent_sr, ent_tg, out2, N);

  // ---- GAT (2 layers, sides merged; dim-major int8 gather) ----
  cvt(ent_sr, A_sr, N, 256, 256, 768);
  cvt(ent_tg, A_tg, N, 256, 256, 768);
  cvtT(gat_W, WtG, 8, 256, 256, 256);
  for (int l = 0; l < 2; ++l) {
    gemm(M_BF16, A_sr + l * 256, WtG + (size_t)l * 1024 * 256, NT2, 768, 256, 256, 8, 1, 1,
         hbuf, nullptr, 1024, nullptr, nullptr, 0, nullptr, nullptr,
         0, 0, 0, 0, 1);
    k_esed<<<NT2, 256, 0, stream>>>(hbuf, gat_as + l * 1024, gat_ad + l * 1024, esqb, edb, q8buf, NT2);
    dim3 gg(1024, 2);
    k_gat<<<gg, 256, 0, stream>>>(q8buf, esqb, edb, off_[0], srcs_[0], off_[1], srcs_[1],
                                  A_sr + (l + 1) * 256, A_tg + (l + 1) * 256, N, NP);
  }

  // ---- MHA precompute ----
  cvt(wq, wqB, 256, 1024, 1024, 1024);
  cvt(wk, wkB, 256, 1024, 1024, 1024);
  cvt(wv, wvB, 256, 1024, 1024, 1024);
  cvtT(fcw, fcT, 1, 1024, 256, 1024);
  k_bias2<<<4, 256, 0, stream>>>(wq, wk, fcw, bq, bk, bv, vq1, vq2, beff2, s3b);
  gemm(M_BF16, wqB, wkB, 256, 1024, 1024, 256, 2, 4, 1, gT, nullptr, 256,
       nullptr, nullptr, 0, nullptr, nullptr, 256, 256, 65536);
  gemm(M_BF16, fcT, wvB, 256, 1024, 1024, 256, 2, 4, 1, vfT, nullptr, 256,
       nullptr, nullptr, 0, nullptr, nullptr, 256, 256, 65536);

  // ---- MHA over ranges + LN + mean (folded, sides merged) ----
  gemm(M_BF16, A_sr, gT, 3 * NT2, 256, 256, 256, 8, 1, 1, kgbuf, nullptr, 1024,
       nullptr, nullptr, 0, nullptr, nullptr, 0, 0, 0, 0, 1);
  {
    dim3 gs(N, 2);
    k_score2<<<gs, 256, 0, stream>>>(A_sr, kgbuf, vq1, vq2, s3b, attn, N, NP);
  }
  gemm(M_BF16B, A_sr, vfT, 3 * NT2, 256, 256, 256, 8, 1, 1, vfbuf, nullptr, 1024,
       nullptr, nullptr, 0, nullptr, beff2, 0, 0, 0, 0, 1);
  {
    dim3 gc(N, 2);
    k_cln<<<gc, 256, 0, stream>>>(vfbuf, attn, A_sr, fcb, lng, lnb, out0, out1, N, NP);
  }
}

// Round 10
// 1720.802 us; speedup vs baseline: 1.0012x; 1.0012x over previous
//
#include <hip/hip_runtime.h>
#include <stdint.h>

typedef unsigned short u16;
typedef __bf16 bf16x8 __attribute__((ext_vector_type(8)));
typedef float f32x4 __attribute__((ext_vector_type(4)));

#define DEV static __device__ __forceinline__

DEV float bf2f(u16 u) { unsigned v = ((unsigned)u) << 16; float f; __builtin_memcpy(&f, &v, 4); return f; }
DEV u16 f2bf(float f) {
  unsigned x; __builtin_memcpy(&x, &f, 4);
  x += 0x7FFFu + ((x >> 16) & 1u);            // round-to-nearest-even
  return (u16)(x >> 16);
}
DEV float wred_sum(float v) { for (int m = 32; m; m >>= 1) v += __shfl_xor(v, m); return v; }
DEV float wred_max(float v) { for (int m = 32; m; m >>= 1) v = fmaxf(v, __shfl_xor(v, m)); return v; }
DEV void wred_max4(f32x4& v) {
  for (int m = 32; m; m >>= 1) {
#pragma unroll
    for (int i = 0; i < 4; ++i) v[i] = fmaxf(v[i], __shfl_xor(v[i], m));
  }
}
DEV void wred_sum4(f32x4& v) {
  for (int m = 32; m; m >>= 1) {
#pragma unroll
    for (int i = 0; i < 4; ++i) v[i] += __shfl_xor(v[i], m);
  }
}

// ---------------- GEMM: C[M,N] = A[M,K] @ Bt[N,K]^T  (A,Bt bf16; acc f32) ----------------
// head-mode (hA|hB|hC != 0): blockIdx.z = h*nsplit + sp; A/B/ein offset by h, K-range by sp.
// swzn != 0: 1-D grid.x = nrt*swzn, XCD-banded bijective mapping, col-fastest within band
// (same row-tile's col blocks run consecutively on one XCD -> A tile L2-hit, B panel L2-resident).
enum { M_ATOMIC = 0, M_SCALE2, M_BLEND, M_BF16, M_BF16B, M_F32B, M_PART };

template <int MODE>
__global__ __launch_bounds__(256) void k_gemm(
    const u16* __restrict__ A, const u16* __restrict__ B,
    int M, int lda, int ldb, int Ksteps, int kper,
    void* __restrict__ C1v, float* __restrict__ C2, int ldc,
    const float* __restrict__ rowsum, const float* __restrict__ ein, int ldein,
    const float* __restrict__ alphap, const float* __restrict__ bias,
    long hA, long hB, long hC, int nsplit, long hE, int swzn)
{
  __shared__ u16 As[4096], Bs[4096];
  const int tid = threadIdx.x, lane = tid & 63, wid = tid >> 6;
  long m0, n0;
  if (swzn) {
    int total = gridDim.x;
    int x = blockIdx.x & 7, jj = blockIdx.x >> 3;
    int q = total >> 3, rb = total & 7;
    int st = x * q + (x < rb ? x : rb);
    int s = st + jj;
    int rowt = s / swzn;
    m0 = (long)rowt * 128;
    n0 = (long)(s - rowt * swzn) * 128;
  } else {
    m0 = (long)blockIdx.x * 128;
    n0 = (long)blockIdx.y * 128;
  }
  int ks, kend;
  long chead = 0;
  int hz = 0;
  if (hA | hB | hC) {
    int z = blockIdx.z;
    hz = z / nsplit;
    int sp = z - hz * nsplit;
    A += (long)hz * hA;
    B += (long)hz * hB;
    chead = (MODE == M_PART) ? (long)z * hC : (long)hz * hC;
    ks = sp * kper;
    kend = ks + kper; if (kend > Ksteps) kend = Ksteps;
  } else {
    ks = blockIdx.z * kper;
    kend = ks + kper; if (kend > Ksteps) kend = Ksteps;
  }
  if (MODE == M_BLEND) ein += (long)hz * hE;

  const u16 *ag[2], *bg[2];
  u16 *al[2], *bl[2];
#pragma unroll
  for (int i = 0; i < 2; ++i) {
    int s = (wid * 2 + i) * 64 + lane;
    int row = s >> 2, cs = (s & 3) ^ ((row >> 1) & 3);
    ag[i] = A + (m0 + row) * (long)lda + cs * 8;
    bg[i] = B + (n0 + row) * (long)ldb + cs * 8;
    al[i] = As + (wid * 2 + i) * 512;
    bl[i] = Bs + (wid * 2 + i) * 512;
  }
  const int kq = lane >> 4, rr = lane & 15;
  const int wm = wid >> 1, wn = wid & 1;

  f32x4 acc[4][4] = {};

  for (; ks < kend; ++ks) {
    long ko = (long)ks * 32;
#pragma unroll
    for (int i = 0; i < 2; ++i) {
      __builtin_amdgcn_global_load_lds((const __attribute__((address_space(1))) unsigned int*)(ag[i] + ko),
                                       (__attribute__((address_space(3))) unsigned int*)al[i], 16, 0, 0);
      __builtin_amdgcn_global_load_lds((const __attribute__((address_space(1))) unsigned int*)(bg[i] + ko),
                                       (__attribute__((address_space(3))) unsigned int*)bl[i], 16, 0, 0);
    }
    __syncthreads();
    bf16x8 af[4], bff[4];
#pragma unroll
    for (int i = 0; i < 4; ++i) {
      int ra = wm * 64 + i * 16 + rr, ca = kq ^ ((ra >> 1) & 3);
      af[i] = *(const bf16x8*)(As + ra * 32 + ca * 8);
      int rb = wn * 64 + i * 16 + rr, cb = kq ^ ((rb >> 1) & 3);
      bff[i] = *(const bf16x8*)(Bs + rb * 32 + cb * 8);
    }
#pragma unroll
    for (int i = 0; i < 4; ++i)
#pragma unroll
      for (int j = 0; j < 4; ++j)
        acc[i][j] = __builtin_amdgcn_mfma_f32_16x16x32_bf16(af[i], bff[j], acc[i][j], 0, 0, 0);
    __syncthreads();
  }

  float* Cf = (float*)C1v;
  u16* Cu = (u16*)C1v;
  const int r4 = (lane >> 4) << 2;
#pragma unroll
  for (int i = 0; i < 4; ++i) {
#pragma unroll
    for (int rg = 0; rg < 4; ++rg) {
      long row = m0 + wm * 64 + i * 16 + r4 + rg;
      if (row >= M) continue;
      float scale = 0.f, al_ = 0.f, ml_ = 0.f;
      if (MODE == M_SCALE2) scale = 1.f / (rowsum[(long)hz * M + row] + 1e-5f);
      if (MODE == M_BLEND) { al_ = *alphap; ml_ = 1.f - al_; }
#pragma unroll
      for (int j = 0; j < 4; ++j) {
        long col = n0 + wn * 64 + j * 16 + rr;
        float v = acc[i][j][rg];
        long idx = chead + row * (long)ldc + col;
        if (MODE == M_ATOMIC) atomicAdd(Cf + idx, v);
        else if (MODE == M_PART) Cf[idx] = v;
        else if (MODE == M_SCALE2) { float sv = v * scale; Cf[idx] = sv; C2[idx] = sv; }
        else if (MODE == M_BLEND) { float e = ein[row * (long)ldein + col]; Cf[idx] = fmaxf(al_ * v + ml_ * e, 0.f); }
        else if (MODE == M_BF16) Cu[idx] = f2bf(v);
        else if (MODE == M_BF16B) Cu[idx] = f2bf(v + bias[col]);
        else if (MODE == M_F32B) Cf[idx] = v + bias[col];
      }
    }
  }
}

// ---------------- converters ----------------
__global__ void k_cvt(const float* __restrict__ in, u16* __restrict__ out, long R, long C, long Cp, long ostride)
{
  long idx = (long)blockIdx.x * blockDim.x + threadIdx.x;
  long cw = Cp >> 3;
  if (idx >= R * cw) return;
  long r = idx / cw, c8 = (idx % cw) << 3;
  u16 tmp[8];
  if (c8 < C) {
    const f32x4* p = (const f32x4*)(in + r * C + c8);
    f32x4 a = p[0], b = p[1];
#pragma unroll
    for (int i = 0; i < 4; ++i) { tmp[i] = f2bf(a[i]); tmp[4 + i] = f2bf(b[i]); }
  } else {
#pragma unroll
    for (int i = 0; i < 8; ++i) tmp[i] = 0;
  }
  uint4 w_; __builtin_memcpy(&w_, tmp, 16);
  *(uint4*)(out + r * ostride + c8) = w_;
}

__global__ __launch_bounds__(256) void k_cvtT(const float* __restrict__ in, u16* __restrict__ out,
                                              int Bh, int R, int C, int Rp)
{
  __shared__ float tile[64][65];
  int bid = blockIdx.x;
  int nrt = Rp >> 6;
  int rt = bid % nrt; bid /= nrt;
  int nct = C >> 6;
  int ct = bid % nct; int b = bid / nct;
  int t = threadIdx.x;
  int tr = t >> 4, tc4 = (t & 15) << 2;
#pragma unroll
  for (int i = 0; i < 4; ++i) {
    int r = (rt << 6) + tr + i * 16;
    f32x4 v = {0.f, 0.f, 0.f, 0.f};
    if (r < R) v = *(const f32x4*)(in + ((long)b * R + r) * C + (ct << 6) + tc4);
    tile[tr + i * 16][tc4 + 0] = v[0];
    tile[tr + i * 16][tc4 + 1] = v[1];
    tile[tr + i * 16][tc4 + 2] = v[2];
    tile[tr + i * 16][tc4 + 3] = v[3];
  }
  __syncthreads();
  int wc = t >> 4, wr4 = (t & 15) << 2;
#pragma unroll
  for (int i = 0; i < 4; ++i) {
    int c = wc + i * 16;
    u16 o[4];
#pragma unroll
    for (int k2 = 0; k2 < 4; ++k2) o[k2] = f2bf(tile[wr4 + k2][c]);
    unsigned long long pk; __builtin_memcpy(&pk, o, 8);
    *(unsigned long long*)(out + ((long)b * C + (ct << 6) + c) * Rp + (rt << 6) + wr4) = pk;
  }
}

// 4 adjacency planes: f32 [N][C] -> bf16 planes + per-plane rowsum
__global__ __launch_bounds__(256) void k_adj4(const float* __restrict__ a0, const float* __restrict__ a1,
                                              const float* __restrict__ a2, const float* __restrict__ a3,
                                              u16* __restrict__ o01, u16* __restrict__ o23,
                                              float* __restrict__ rowsum, int C, int Cp, int N)
{
  int r = blockIdx.x, pl = blockIdx.y, t = threadIdx.x;
  const float* in = pl == 0 ? a0 : pl == 1 ? a1 : pl == 2 ? a2 : a3;
  u16* out = pl < 2 ? o01 + (size_t)pl * N * Cp : o23 + (size_t)(pl - 2) * N * Cp;
  f32x4 v = {0.f, 0.f, 0.f, 0.f};
  int c = t << 2;
  if (c + 3 < C) v = *(const f32x4*)(in + (long)r * C + c);
  u16 o[4];
#pragma unroll
  for (int i = 0; i < 4; ++i) o[i] = f2bf(v[i]);
  unsigned long long pk; __builtin_memcpy(&pk, o, 8);
  *(unsigned long long*)(out + (long)r * Cp + c) = pk;
  float s = wred_sum(v[0] + v[1] + v[2] + v[3]);
  __shared__ float ws4[4];
  if ((t & 63) == 0) ws4[t >> 6] = s;
  __syncthreads();
  if (t == 0) rowsum[(long)pl * N + r] = ws4[0] + ws4[1] + ws4[2] + ws4[3];
}

// reduce NS partial planes: o[h][i] = sum_sp P[h*NS+sp][i], plane = 32768 f32
__global__ void k_red(const float* __restrict__ P, float* __restrict__ o, int NS)
{
  int i = blockIdx.x * 256 + threadIdx.x;         // 0..65535
  int h = i >> 15, rem = i & 32767;
  const float* p = P + (long)h * NS * 32768 + rem;
  float s = 0.f;
  for (int k = 0; k < NS; ++k) s += p[(long)k * 32768];
  o[i] = s;
}

// ---------------- CSR build ----------------
__global__ void k_zero_i(int* p, int n) { for (int i = blockIdx.x * blockDim.x + threadIdx.x; i < n; i += gridDim.x * blockDim.x) p[i] = 0; }
__global__ void k_copy_i(const int* __restrict__ a, int* __restrict__ b, int n) { for (int i = blockIdx.x * blockDim.x + threadIdx.x; i < n; i += gridDim.x * blockDim.x) b[i] = a[i]; }
__global__ void k_hist(const int* __restrict__ dst, int* __restrict__ deg, int E)
{ for (int i = blockIdx.x * blockDim.x + threadIdx.x; i < E; i += gridDim.x * blockDim.x) atomicAdd(&deg[dst[i]], 1); }
__global__ void k_scatter(const int* __restrict__ src, const int* __restrict__ dst, int* __restrict__ cur,
                          int* __restrict__ srcs, int E)
{
  for (int i = blockIdx.x * blockDim.x + threadIdx.x; i < E; i += gridDim.x * blockDim.x) {
    int p = atomicAdd(&cur[dst[i]], 1);
    srcs[p] = src[i];
  }
}
// single-block scan: per-thread serial chunk + LDS scan + serial writeback
__global__ __launch_bounds__(1024) void k_scan(const int* __restrict__ deg, int* __restrict__ off, int n)
{
  __shared__ int bsum[1024];
  int t = threadIdx.x;
  int per = (n + 1023) >> 10;
  int s0 = t * per, s1 = s0 + per; if (s1 > n) s1 = n;
  int s = 0;
  for (int i = s0; i < s1; ++i) s += deg[i];
  bsum[t] = s;
  __syncthreads();
  for (int d = 1; d < 1024; d <<= 1) {
    int x = (t >= d) ? bsum[t - d] : 0;
    __syncthreads();
    bsum[t] += x;
    __syncthreads();
  }
  if (t == 0) off[0] = 0;
  int run = t ? bsum[t - 1] : 0;
  for (int i = s0; i < s1; ++i) { run += deg[i]; off[i + 1] = run; }
}

// ---------------- GAT ----------------
// es/ed dots + fused int8 row quantization; q8 layout is DIM-MAJOR: row byte = d*4 + hd
__global__ __launch_bounds__(256) void k_esed(const u16* __restrict__ h, const float* __restrict__ as_,
                                              const float* __restrict__ ad_, float* __restrict__ esq,
                                              float* __restrict__ ed, signed char* __restrict__ q8, int N)
{
  __shared__ int stg[4][64];
  int n = blockIdx.x, t = threadIdx.x, hd = t >> 6, l = t & 63;
  long base = (long)n * 1024 + hd * 256 + (l << 2);
  ushort4 hv = *(const ushort4*)(h + base);
  float h0 = bf2f(hv.x), h1 = bf2f(hv.y), h2 = bf2f(hv.z), h3 = bf2f(hv.w);
  const float* ap = as_ + hd * 256 + (l << 2);
  const float* dp = ad_ + hd * 256 + (l << 2);
  float ps = h0 * ap[0] + h1 * ap[1] + h2 * ap[2] + h3 * ap[3];
  float pd = h0 * dp[0] + h1 * dp[1] + h2 * dp[2] + h3 * dp[3];
  ps = wred_sum(ps); pd = wred_sum(pd);
  float amax = fmaxf(fmaxf(fabsf(h0), fabsf(h1)), fmaxf(fabsf(h2), fabsf(h3)));
  amax = wred_max(amax);
  float rsc = amax > 0.f ? 127.f / amax : 0.f;
  signed char qb[4];
  qb[0] = (signed char)__float2int_rn(h0 * rsc);
  qb[1] = (signed char)__float2int_rn(h1 * rsc);
  qb[2] = (signed char)__float2int_rn(h2 * rsc);
  qb[3] = (signed char)__float2int_rn(h3 * rsc);
  int qw; __builtin_memcpy(&qw, qb, 4);
  stg[hd][l] = qw;
  if (l == 0) {
    esq[n * 8 + hd] = ps;
    esq[n * 8 + 4 + hd] = amax * (1.f / 127.f);
    ed[n * 4 + hd] = pd;
  }
  __syncthreads();
  if (t < 64) {
    int b0 = stg[0][t], b1 = stg[1][t], b2 = stg[2][t], b3 = stg[3][t];
    unsigned r[4];
#pragma unroll
    for (int i = 0; i < 4; ++i) {
      int sh = 8 * i;
      r[i] = ((unsigned)((b0 >> sh) & 0xff)) | ((unsigned)((b1 >> sh) & 0xff) << 8) |
             ((unsigned)((b2 >> sh) & 0xff) << 16) | ((unsigned)((b3 >> sh) & 0xff) << 24);
    }
    uint4 o; __builtin_memcpy(&o, r, 16);
    *(uint4*)(q8 + (long)n * 1024 + (t << 4)) = o;
  }
}

// persistent wave-per-node softmax aggregation; dim-major int8 gather;
// LDS broadcast of (weights, src). grid (1024, 2 sides), wave-strided node loop.
__global__ __launch_bounds__(256) void k_gat(const signed char* __restrict__ q8,
                                             const float* __restrict__ esq, const float* __restrict__ ed,
                                             const int* __restrict__ off0, const int* __restrict__ srcs0,
                                             const int* __restrict__ off1, const int* __restrict__ srcs1,
                                             u16* __restrict__ x0, u16* __restrict__ x1, int N, int NPq)
{
  __shared__ f32x4 sw[4][64];
  __shared__ int ss[4][64];
  int t = threadIdx.x, w = t >> 6, l = t & 63;
  int side = blockIdx.y;
  const int* off = side ? off1 : off0;
  const int* srcs = side ? srcs1 : srcs0;
  u16* xout = side ? x1 : x0;
  size_t ofs = side ? (size_t)NPq : 0;
  q8 += ofs * 1024; esq += ofs * 8;
  const long loff = l << 2;
  const int nstride = gridDim.x * 4;

  for (int n = blockIdx.x * 4 + w; n < N; n += nstride) {
    int e0 = off[n], deg = off[n + 1] - e0;
    f32x4 edv = *(const f32x4*)(ed + (ofs + n) * 4);

    f32x4 m = {-1e30f, -1e30f, -1e30f, -1e30f};
    f32x4 psum = {0.f, 0.f, 0.f, 0.f};
    f32x4 acc0 = {0.f, 0.f, 0.f, 0.f};
    f32x4 acc1 = {0.f, 0.f, 0.f, 0.f};
    f32x4 acc2 = {0.f, 0.f, 0.f, 0.f};
    f32x4 acc3 = {0.f, 0.f, 0.f, 0.f};

    for (int base = 0; base < deg; base += 64) {
      int cnt = min(64, deg - base);
      bool act = l < cnt;
      int s = 0;
      f32x4 v = {-1e30f, -1e30f, -1e30f, -1e30f};
      if (act) {
        s = srcs[e0 + base + l];
        f32x4 es4 = *(const f32x4*)(esq + (long)s * 8);
#pragma unroll
        for (int hd = 0; hd < 4; ++hd) {
          float x = es4[hd] + edv[hd];
          v[hd] = x >= 0.f ? x : 0.2f * x;
        }
      }
      f32x4 mc = v;
      wred_max4(mc);
      f32x4 nm;
#pragma unroll
      for (int hd = 0; hd < 4; ++hd) nm[hd] = fmaxf(m[hd], mc[hd]);
      f32x4 sc;
#pragma unroll
      for (int hd = 0; hd < 4; ++hd) sc[hd] = __expf(m[hd] - nm[hd]);
      psum *= sc;
      acc0 *= sc[0]; acc1 *= sc[1]; acc2 *= sc[2]; acc3 *= sc[3];
      m = nm;
      f32x4 wq4 = {0.f, 0.f, 0.f, 0.f};
      if (act) {
        f32x4 qs4 = *(const f32x4*)(esq + (long)s * 8 + 4);
#pragma unroll
        for (int hd = 0; hd < 4; ++hd) {
          float e = __expf(v[hd] - m[hd]);
          psum[hd] += e;
          wq4[hd] = e * qs4[hd];
        }
      }
      sw[w][l] = wq4;
      ss[w][l] = s;
#pragma unroll 4
      for (int j = 0; j < cnt; ++j) {
        f32x4 w4 = sw[w][j];
        int sj = ss[w][j];
        uint4 c = *(const uint4*)(q8 + (long)sj * 1024 + (l << 4));
        const int* cw = (const int*)&c;
#pragma unroll
        for (int i = 0; i < 4; ++i) {
          int ci = cw[i];
          acc0[i] += w4[0] * (float)((signed char)(ci));
          acc1[i] += w4[1] * (float)((signed char)(ci >> 8));
          acc2[i] += w4[2] * (float)((signed char)(ci >> 16));
          acc3[i] += w4[3] * (float)(ci >> 24);
        }
      }
    }
    wred_sum4(psum);
    f32x4 rd;
#pragma unroll
    for (int hd = 0; hd < 4; ++hd) rd[hd] = 1.f / (psum[hd] + 1e-16f);
    float mean[4]; float nrm = 0.f;
#pragma unroll
    for (int i = 0; i < 4; ++i) {
      float y0 = acc0[i] * rd[0]; y0 = y0 > 0.f ? y0 : __expf(y0) - 1.f;
      float y1 = acc1[i] * rd[1]; y1 = y1 > 0.f ? y1 : __expf(y1) - 1.f;
      float y2 = acc2[i] * rd[2]; y2 = y2 > 0.f ? y2 : __expf(y2) - 1.f;
      float y3 = acc3[i] * rd[3]; y3 = y3 > 0.f ? y3 : __expf(y3) - 1.f;
      float mv = 0.25f * (y0 + y1 + y2 + y3);
      mean[i] = mv; nrm += mv * mv;
    }
    nrm = wred_sum(nrm);
    float scn = 1.f / fmaxf(sqrtf(nrm), 1e-12f);
    u16 o[4];
#pragma unroll
    for (int i = 0; i < 4; ++i) o[i] = f2bf(mean[i] * scn);
    unsigned long long pk; __builtin_memcpy(&pk, o, 8);
    *(unsigned long long*)(xout + (long)n * 768 + loff) = pk;
  }
}

// ---------------- MHA (folded) ----------------
__global__ void k_bias2(const float* __restrict__ wq, const float* __restrict__ wk,
                        const float* __restrict__ fcw,
                        const float* __restrict__ bq, const float* __restrict__ bk,
                        const float* __restrict__ bv,
                        float* __restrict__ vq1, float* __restrict__ vq2,
                        float* __restrict__ beff2, float* __restrict__ s3)
{
  int t = blockIdx.x * 256 + threadIdx.x;   // 0..1023
  int h = t >> 8, d = t & 255;
  float a1 = 0.f, a2 = 0.f, a3 = 0.f;
  for (int j = 0; j < 256; ++j) {
    a1 += wk[(long)d * 1024 + h * 256 + j] * bq[h * 256 + j];
    a2 += wq[(long)d * 1024 + h * 256 + j] * bk[h * 256 + j];
    a3 += bv[h * 256 + j] * fcw[(long)(h * 256 + j) * 256 + d];
  }
  vq1[t] = a1; vq2[t] = a2; beff2[t] = a3;
  if (d == 0) {
    float s = 0.f;
    for (int j = 0; j < 256; ++j) s += bq[h * 256 + j] * bk[h * 256 + j];
    s3[h] = s;
  }
}

// per-node scores; grid (N, 2 sides)
__global__ __launch_bounds__(256) void k_score2(const u16* __restrict__ x, const u16* __restrict__ kg,
                                                const float* __restrict__ vq1, const float* __restrict__ vq2,
                                                const float* __restrict__ s3, float* __restrict__ attn,
                                                int N, int NPq)
{
  int n = blockIdx.x, side = blockIdx.y, t = threadIdx.x, hd = t >> 6, l = t & 63;
  long rbase = (long)side * 3 * NPq + (long)n * 3;
  int i4 = l << 2;
  f32x4 xr[3], kc[3];
#pragma unroll
  for (int r = 0; r < 3; ++r) {
    ushort4 a = *(const ushort4*)(x + (rbase + r) * 256 + i4);
    xr[r][0] = bf2f(a.x); xr[r][1] = bf2f(a.y); xr[r][2] = bf2f(a.z); xr[r][3] = bf2f(a.w);
    ushort4 b = *(const ushort4*)(kg + (rbase + r) * 1024 + hd * 256 + i4);
    kc[r][0] = bf2f(b.x); kc[r][1] = bf2f(b.y); kc[r][2] = bf2f(b.z); kc[r][3] = bf2f(b.w);
  }
  f32x4 v1 = *(const f32x4*)(vq1 + hd * 256 + i4);
  f32x4 v2 = *(const f32x4*)(vq2 + hd * 256 + i4);
  float red[15];
#pragma unroll
  for (int r = 0; r < 3; ++r)
#pragma unroll
    for (int c = 0; c < 3; ++c) {
      f32x4 p = xr[r] * kc[c];
      red[r * 3 + c] = p[0] + p[1] + p[2] + p[3];
    }
#pragma unroll
  for (int c = 0; c < 3; ++c) {
    f32x4 p1 = xr[c] * v1;
    f32x4 p2 = xr[c] * v2;
    red[9 + c] = p1[0] + p1[1] + p1[2] + p1[3];
    red[12 + c] = p2[0] + p2[1] + p2[2] + p2[3];
  }
#pragma unroll
  for (int i = 0; i < 15; ++i) red[i] = wred_sum(red[i]);
  if (l == 0) {
    float s3h = s3[hd];
    float* out = attn + ((long)side * N + n) * 36 + hd * 9;
#pragma unroll
    for (int r = 0; r < 3; ++r) {
      float v0 = (red[r * 3 + 0] + red[9 + 0] + red[12 + r] + s3h) * 0.0625f;
      float v1_ = (red[r * 3 + 1] + red[9 + 1] + red[12 + r] + s3h) * 0.0625f;
      float v2_ = (red[r * 3 + 2] + red[9 + 2] + red[12 + r] + s3h) * 0.0625f;
      float mm = fmaxf(v0, fmaxf(v1_, v2_));
      float e0 = __expf(v0 - mm), e1 = __expf(v1_ - mm), e2 = __expf(v2_ - mm);
      float rs = 1.f / (e0 + e1 + e2);
      out[r * 3 + 0] = e0 * rs; out[r * 3 + 1] = e1 * rs; out[r * 3 + 2] = e2 * rs;
    }
  }
}

// fused combine + fc-bias + residual + LayerNorm + range-mean; grid (N, 2 sides)
__global__ __launch_bounds__(256) void k_cln(const u16* __restrict__ vf, const float* __restrict__ attn,
                                             const u16* __restrict__ x, const float* __restrict__ fcb,
                                             const float* __restrict__ g, const float* __restrict__ b,
                                             float* __restrict__ out0, float* __restrict__ out1,
                                             int N, int NPq)
{
  int n = blockIdx.x, side = blockIdx.y, t = threadIdx.x, w = t >> 6, l = t & 63;
  long rbase = (long)side * 3 * NPq + (long)n * 3;
  float* out = (side ? out1 : out0) + (long)n * 768;
  __shared__ float aa[36];
  __shared__ float ybuf[3][256];
  if (t < 36) aa[t] = attn[((long)side * N + n) * 36 + t];
  __syncthreads();
  if (w < 3) {
    int d4 = l << 2;
    f32x4 acc = {0.f, 0.f, 0.f, 0.f};
#pragma unroll
    for (int h = 0; h < 4; ++h)
#pragma unroll
      for (int rp = 0; rp < 3; ++rp) {
        float wgt = aa[h * 9 + w * 3 + rp];
        ushort4 vv = *(const ushort4*)(vf + (rbase + rp) * 1024 + h * 256 + d4);
        acc[0] += wgt * bf2f(vv.x); acc[1] += wgt * bf2f(vv.y);
        acc[2] += wgt * bf2f(vv.z); acc[3] += wgt * bf2f(vv.w);
      }
    f32x4 fb = *(const f32x4*)(fcb + d4);
    ushort4 xu = *(const ushort4*)(x + (rbase + w) * 256 + d4);
    acc[0] += fb[0] + bf2f(xu.x); acc[1] += fb[1] + bf2f(xu.y);
    acc[2] += fb[2] + bf2f(xu.z); acc[3] += fb[3] + bf2f(xu.w);
    float s1 = acc[0] + acc[1] + acc[2] + acc[3];
    float s2 = acc[0] * acc[0] + acc[1] * acc[1] + acc[2] * acc[2] + acc[3] * acc[3];
    s1 = wred_sum(s1); s2 = wred_sum(s2);
    float mu = s1 * 0.00390625f;
    float var = s2 * 0.00390625f - mu * mu;
    float rs = rsqrtf(var + 1e-5f);
#pragma unroll
    for (int i = 0; i < 4; ++i) {
      int d = d4 + i;
      ybuf[w][d] = (acc[i] - mu) * rs * g[d] + b[d];
    }
  }
  __syncthreads();
  if (t < 64) {
#pragma unroll
    for (int i = 0; i < 4; ++i) {
      int d = (t << 2) + i;
      out[d] = (ybuf[0][d] + ybuf[1][d] + ybuf[2][d]) * (1.f / 3.f);
    }
  }
}

// aug = e + ent, both sides; out2/out3 contiguous
__global__ void k_aug(const float* __restrict__ e, const float* __restrict__ ent0,
                      const float* __restrict__ ent1, float* __restrict__ out, int N)
{
  long i = (long)blockIdx.x * blockDim.x + threadIdx.x;
  if (i >= (long)N * 128) return;
  int side = i >= (long)N * 64;
  long ii = side ? i - (long)N * 64 : i;
  const float* ent = side ? ent1 : ent0;
  long n = ii >> 6; int d4 = (int)(ii & 63) << 2;
  f32x4 a = *(const f32x4*)(e + ((long)side * N + n) * 256 + d4);
  f32x4 c = *(const f32x4*)(ent + n * 256 + d4);
  *(f32x4*)(out + ((long)side * N + n) * 768 + d4) = a + c;
}

// ---------------- host ----------------
extern "C" void kernel_launch(void* const* d_in, const int* in_sizes, int n_in,
                              void* d_out, int out_size, void* d_ws, size_t ws_size,
                              hipStream_t stream)
{
  (void)n_in; (void)out_size; (void)ws_size;
  const int N = 20000, NP = 20096, RNUM = 1000, RP = 1024;
  const int NT2 = NP + N;
  const int NS = 64;
  const int Es = in_sizes[26] / 2, Et = in_sizes[27] / 2;

  const float* ent_sr = (const float*)d_in[0];
  const float* ent_tg = (const float*)d_in[1];
  const float* rel_in[2] = {(const float*)d_in[2], (const float*)d_in[3]};
  const float* alphap = (const float*)d_in[4];
  const float* ums[2] = {(const float*)d_in[5], (const float*)d_in[7]};
  const float* vt[2]  = {(const float*)d_in[6], (const float*)d_in[8]};
  const float* adj[4] = {(const float*)d_in[9], (const float*)d_in[10], (const float*)d_in[11], (const float*)d_in[12]};
  const float* gat_W  = (const float*)d_in[13];
  const float* gat_as = (const float*)d_in[14];
  const float* gat_ad = (const float*)d_in[15];
  const float* wq = (const float*)d_in[16]; const float* bq = (const float*)d_in[17];
  const float* wk = (const float*)d_in[18]; const float* bk = (const float*)d_in[19];
  const float* wv = (const float*)d_in[20]; const float* bv = (const float*)d_in[21];
  const float* fcw = (const float*)d_in[22]; const float* fcb = (const float*)d_in[23];
  const float* lng = (const float*)d_in[24]; const float* lnb = (const float*)d_in[25];
  const int* edges[2] = {(const int*)d_in[26], (const int*)d_in[27]};
  const int Ecnt[2] = {Es, Et};

  float* out0 = (float*)d_out;
  float* out1 = out0 + (size_t)N * 768;
  float* out2 = out1 + (size_t)N * 768;
  float* out3 = out2 + (size_t)N * 768;

  char* wsp = (char*)d_ws; size_t wo = 0;
  auto alloc = [&](size_t bytes) { void* p = wsp + wo; wo = (wo + bytes + 255) & ~(size_t)255; return p; };

  u16* A_sr = (u16*)alloc((size_t)NP * 768 * 2);
  u16* A_tg = (u16*)alloc((size_t)NP * 768 * 2);     // contiguous after A_sr (size % 256 == 0)
  u16* QBUF = (u16*)alloc((size_t)3 * NT2 * 1024 * 2);  // 246 MB: rel adj 0/1, GAT h, vf
  u16* KBUF = (u16*)alloc((size_t)3 * NT2 * 1024 * 2);  // 246 MB: rel adj 2/3, SVD scratch, q8, kg
  float* PART = (float*)alloc((size_t)2 * NS * 32768 * 4);
  float* rowsum = (float*)alloc((size_t)4 * N * 4);
  u16* relT[2] = {(u16*)alloc(256 * RP * 2), (u16*)alloc(256 * RP * 2)};
  u16* WtG = (u16*)alloc((size_t)2 * 1024 * 256 * 2);
  u16* fcT = (u16*)alloc(256 * 1024 * 2);
  u16* wqB = (u16*)alloc(256 * 1024 * 2);
  u16* wkB = (u16*)alloc(256 * 1024 * 2);
  u16* wvB = (u16*)alloc(256 * 1024 * 2);
  u16* gT  = (u16*)alloc((size_t)4 * 256 * 256 * 2);
  u16* vfT = (u16*)alloc((size_t)4 * 256 * 256 * 2);
  float* vq1 = (float*)alloc(1024 * 4);
  float* vq2 = (float*)alloc(1024 * 4);
  float* beff2 = (float*)alloc(1024 * 4);
  float* s3b = (float*)alloc(4 * 4);
  float* esqb = (float*)alloc((size_t)NT2 * 8 * 4);
  float* edb = (float*)alloc((size_t)NT2 * 4 * 4);
  float* attn = (float*)alloc((size_t)2 * N * 36 * 4);
  int* off_[2]; int* cur_[2]; int* srcs_[2];
  for (int s = 0; s < 2; ++s) {
    off_[s] = (int*)alloc((size_t)(N + 4) * 4);
    cur_[s] = (int*)alloc((size_t)(N + 4) * 4);
    srcs_[s] = (int*)alloc((size_t)Ecnt[s] * 4);
  }
  float* tT2 = (float*)alloc((size_t)2 * 256 * 128 * 4);
  u16* tTb2 = (u16*)alloc((size_t)2 * 256 * 128 * 2);

  // aliases
  u16* hbuf = QBUF;                 // GAT phase
  u16* vfbuf = QBUF;                // MHA phase
  u16* adjbQ = QBUF;                // rel planes 0,1
  u16* adjbK = KBUF;                // rel planes 2,3
  float* e_b = (float*)KBUF;        // SVD: [2][N][256] f32
  u16* eT = (u16*)(e_b + (size_t)2 * N * 256);   // [2][256][NP]
  u16* vtb0 = eT + (size_t)2 * 256 * NP;         // [2][128][NP]
  u16* umb0 = vtb0 + (size_t)2 * 128 * NP;       // [2][NP][128] (rows 0..N used)
  signed char* q8buf = (signed char*)KBUF;       // GAT phase (dim-major int8)
  u16* kgbuf = KBUF;                             // MHA phase

  const float* ent_s[2] = {ent_sr, ent_tg};

  auto cvt = [&](const float* in, u16* out, long R, long C, long Cp, long ostr) {
    long total = R * (Cp >> 3);
    int blocks = (int)((total + 255) / 256);
    k_cvt<<<blocks, 256, 0, stream>>>(in, out, R, C, Cp, ostr);
  };
  auto cvtT = [&](const float* in, u16* out, int Bh, int R, int C, int Rp) {
    int blocks = (Rp >> 6) * (C >> 6) * Bh;
    k_cvtT<<<blocks, 256, 0, stream>>>(in, out, Bh, R, C, Rp);
  };
  auto gemm = [&](int mode, const u16* A, const u16* B, int M, int lda, int ldb, int Kp, int Nt,
                  int zdim, int nsplit,
                  void* C1, float* C2, int ldc, const float* rs, const float* ein, int ldein,
                  const float* alp, const float* bias,
                  long hA = 0, long hB = 0, long hC = 0, long hE = 0, int swz = 0) {
    int Ks = Kp >> 5;
    bool hmode = (hA | hB | hC) != 0;
    int kper = hmode ? (Ks + nsplit - 1) / nsplit
                     : (zdim > 1 ? (Ks + zdim - 1) / zdim : Ks);
    int nrt = (M + 127) >> 7;
    dim3 g(nrt, Nt, zdim);
    int swzn = 0;
    if (swz && !hmode && zdim == 1) { g = dim3(nrt * Nt, 1, 1); swzn = Nt; }
    switch (mode) {
      case M_ATOMIC: k_gemm<M_ATOMIC><<<g, 256, 0, stream>>>(A, B, M, lda, ldb, Ks, kper, C1, C2, ldc, rs, ein, ldein, alp, bias, hA, hB, hC, nsplit, hE, swzn); break;
      case M_SCALE2: k_gemm<M_SCALE2><<<g, 256, 0, stream>>>(A, B, M, lda, ldb, Ks, kper, C1, C2, ldc, rs, ein, ldein, alp, bias, hA, hB, hC, nsplit, hE, swzn); break;
      case M_BLEND:  k_gemm<M_BLEND><<<g, 256, 0, stream>>>(A, B, M, lda, ldb, Ks, kper, C1, C2, ldc, rs, ein, ldein, alp, bias, hA, hB, hC, nsplit, hE, swzn); break;
      case M_BF16:   k_gemm<M_BF16><<<g, 256, 0, stream>>>(A, B, M, lda, ldb, Ks, kper, C1, C2, ldc, rs, ein, ldein, alp, bias, hA, hB, hC, nsplit, hE, swzn); break;
      case M_BF16B:  k_gemm<M_BF16B><<<g, 256, 0, stream>>>(A, B, M, lda, ldb, Ks, kper, C1, C2, ldc, rs, ein, ldein, alp, bias, hA, hB, hC, nsplit, hE, swzn); break;
      case M_F32B:   k_gemm<M_F32B><<<g, 256, 0, stream>>>(A, B, M, lda, ldb, Ks, kper, C1, C2, ldc, rs, ein, ldein, alp, bias, hA, hB, hC, nsplit, hE, swzn); break;
      case M_PART:   k_gemm<M_PART><<<g, 256, 0, stream>>>(A, B, M, lda, ldb, Ks, kper, C1, C2, ldc, rs, ein, ldein, alp, bias, hA, hB, hC, nsplit, hE, swzn); break;
    }
  };

  // ---- CSR build (per side) ----
  for (int s = 0; s < 2; ++s) {
    k_zero_i<<<80, 256, 0, stream>>>(cur_[s], N);
    k_hist<<<1024, 256, 0, stream>>>(edges[s] + Ecnt[s], cur_[s], Ecnt[s]);
    k_scan<<<1, 1024, 0, stream>>>(cur_[s], off_[s], N);
    k_copy_i<<<80, 256, 0, stream>>>(off_[s], cur_[s], N);
    k_scatter<<<1024, 256, 0, stream>>>(edges[s], edges[s] + Ecnt[s], cur_[s], srcs_[s], Ecnt[s]);
  }

  // ---- Relation aggregator: one adj pass + two head-mode GEMMs ----
  cvtT(rel_in[0], relT[0], 1, RNUM, 256, RP);
  cvtT(rel_in[1], relT[1], 1, RNUM, 256, RP);
  {
    dim3 ga(N, 4);
    k_adj4<<<ga, 256, 0, stream>>>(adj[0], adj[1], adj[2], adj[3], adjbQ, adjbK, rowsum, RNUM, RP, N);
  }
  gemm(M_SCALE2, adjbQ, relT[0], N, RP, RP, RP, 2, 2, 1,
       out0 + 256, out2 + 256, 768, rowsum, nullptr, 0, nullptr, nullptr,
       (long)N * RP, 0, 256);
  gemm(M_SCALE2, adjbK, relT[1], N, RP, RP, RP, 2, 2, 1,
       out1 + 256, out3 + 256, 768, rowsum + 2 * N, nullptr, 0, nullptr, nullptr,
       (long)N * RP, 0, 256);

  // ---- SVD global-structure propagation (sides merged per layer) ----
  cvt(vt[0], vtb0, 128, N, NP, NP);
  cvt(vt[1], vtb0 + (size_t)128 * NP, 128, N, NP, NP);
  cvt(ums[0], umb0, N, 128, 128, 128);
  cvt(ums[1], umb0 + (size_t)NP * 128, N, 128, 128, 128);
  for (int l = 0; l < 2; ++l) {
    if (l == 0) {
      cvtT(ent_sr, eT, 1, N, 256, NP);
      cvtT(ent_tg, eT + (size_t)256 * NP, 1, N, 256, NP);
    } else {
      cvtT(e_b, eT, 2, N, 256, NP);
    }
    gemm(M_PART, eT, vtb0, 256, NP, NP, NP, 1, 2 * NS, NS,
         PART, nullptr, 128, nullptr, nullptr, 0, nullptr, nullptr,
         (long)256 * NP, (long)128 * NP, 32768);
    k_red<<<256, 256, 0, stream>>>(PART, tT2, NS);
    cvt(tT2, tTb2, 512, 128, 128, 128);
    if (l == 0) {
      for (int s = 0; s < 2; ++s)
        gemm(M_BLEND, umb0 + (size_t)s * NP * 128, tTb2 + (size_t)s * 32768, N, 128, 128, 128, 2, 1, 1,
             e_b + (size_t)s * N * 256, nullptr, 256, nullptr, ent_s[s], 256, alphap, nullptr,
             0, 0, 0, 0, 1);
    } else {
      gemm(M_BLEND, umb0, tTb2, N, 128, 128, 128, 2, 2, 1,
           e_b, nullptr, 256, nullptr, e_b, 256, alphap, nullptr,
           (long)NP * 128, 32768, (long)N * 256, (long)N * 256);
    }
  }
  k_aug<<<(int)(((long)N * 128 + 255) / 256), 256, 0, stream>>>(e_b, ent_sr, ent_tg, out2, N);

  // ---- GAT (2 layers, sides merged; dim-major int8 gather) ----
  cvt(ent_sr, A_sr, N, 256, 256, 768);
  cvt(ent_tg, A_tg, N, 256, 256, 768);
  cvtT(gat_W, WtG, 8, 256, 256, 256);
  for (int l = 0; l < 2; ++l) {
    gemm(M_BF16, A_sr + l * 256, WtG + (size_t)l * 1024 * 256, NT2, 768, 256, 256, 8, 1, 1,
         hbuf, nullptr, 1024, nullptr, nullptr, 0, nullptr, nullptr,
         0, 0, 0, 0, 1);
    k_esed<<<NT2, 256, 0, stream>>>(hbuf, gat_as + l * 1024, gat_ad + l * 1024, esqb, edb, q8buf, NT2);
    dim3 gg(1024, 2);
    k_gat<<<gg, 256, 0, stream>>>(q8buf, esqb, edb, off_[0], srcs_[0], off_[1], srcs_[1],
                                  A_sr + (l + 1) * 256, A_tg + (l + 1) * 256, N, NP);
  }

  // ---- MHA precompute ----
  cvt(wq, wqB, 256, 1024, 1024, 1024);
  cvt(wk, wkB, 256, 1024, 1024, 1024);
  cvt(wv, wvB, 256, 1024, 1024, 1024);
  cvtT(fcw, fcT, 1, 1024, 256, 1024);
  k_bias2<<<4, 256, 0, stream>>>(wq, wk, fcw, bq, bk, bv, vq1, vq2, beff2, s3b);
  gemm(M_BF16, wqB, wkB, 256, 1024, 1024, 256, 2, 4, 1, gT, nullptr, 256,
       nullptr, nullptr, 0, nullptr, nullptr, 256, 256, 65536);
  gemm(M_BF16, fcT, wvB, 256, 1024, 1024, 256, 2, 4, 1, vfT, nullptr, 256,
       nullptr, nullptr, 0, nullptr, nullptr, 256, 256, 65536);

  // ---- MHA over ranges + LN + mean (folded, sides merged) ----
  gemm(M_BF16, A_sr, gT, 3 * NT2, 256, 256, 256, 8, 1, 1, kgbuf, nullptr, 1024,
       nullptr, nullptr, 0, nullptr, nullptr, 0, 0, 0, 0, 1);
  {
    dim3 gs(N, 2);
    k_score2<<<gs, 256, 0, stream>>>(A_sr, kgbuf, vq1, vq2, s3b, attn, N, NP);
  }
  gemm(M_BF16B, A_sr, vfT, 3 * NT2, 256, 256, 256, 8, 1, 1, vfbuf, nullptr, 1024,
       nullptr, nullptr, 0, nullptr, beff2, 0, 0, 0, 0, 1);
  {
    dim3 gc(N, 2);
    k_cln<<<gc, 256, 0, stream>>>(vfbuf, attn, A_sr, fcb, lng, lnb, out0, out1, N, NP);
  }
}

// Round 11
// 1702.916 us; speedup vs baseline: 1.0117x; 1.0105x over previous
//
#include <hip/hip_runtime.h>
#include <stdint.h>

typedef unsigned short u16;
typedef __bf16 bf16x8 __attribute__((ext_vector_type(8)));
typedef float f32x4 __attribute__((ext_vector_type(4)));

#define DEV static __device__ __forceinline__

DEV float bf2f(u16 u) { unsigned v = ((unsigned)u) << 16; float f; __builtin_memcpy(&f, &v, 4); return f; }
DEV u16 f2bf(float f) {
  unsigned x; __builtin_memcpy(&x, &f, 4);
  x += 0x7FFFu + ((x >> 16) & 1u);            // round-to-nearest-even
  return (u16)(x >> 16);
}
DEV float wred_sum(float v) { for (int m = 32; m; m >>= 1) v += __shfl_xor(v, m); return v; }
DEV float wred_max(float v) { for (int m = 32; m; m >>= 1) v = fmaxf(v, __shfl_xor(v, m)); return v; }
DEV void wred_max4(f32x4& v) {
  for (int m = 32; m; m >>= 1) {
#pragma unroll
    for (int i = 0; i < 4; ++i) v[i] = fmaxf(v[i], __shfl_xor(v[i], m));
  }
}
DEV void wred_sum4(f32x4& v) {
  for (int m = 32; m; m >>= 1) {
#pragma unroll
    for (int i = 0; i < 4; ++i) v[i] += __shfl_xor(v[i], m);
  }
}

// ---------------- GEMM: C[M,N] = A[M,K] @ Bt[N,K]^T  (A,Bt bf16; acc f32) ----------------
// head-mode (hA|hB|hC != 0): blockIdx.z = h*nsplit + sp; A/B/ein offset by h, K-range by sp.
// swzn != 0: 1-D grid.x = nrt*swzn, XCD-banded bijective mapping, col-fastest within band
// (same row-tile's col blocks run consecutively on one XCD -> A tile L2-hit, B panel L2-resident).
enum { M_ATOMIC = 0, M_SCALE2, M_BLEND, M_BF16, M_BF16B, M_F32B, M_PART };

template <int MODE>
__global__ __launch_bounds__(256) void k_gemm(
    const u16* __restrict__ A, const u16* __restrict__ B,
    int M, int lda, int ldb, int Ksteps, int kper,
    void* __restrict__ C1v, float* __restrict__ C2, int ldc,
    const float* __restrict__ rowsum, const float* __restrict__ ein, int ldein,
    const float* __restrict__ alphap, const float* __restrict__ bias,
    long hA, long hB, long hC, int nsplit, long hE, int swzn)
{
  __shared__ u16 As[4096], Bs[4096];
  const int tid = threadIdx.x, lane = tid & 63, wid = tid >> 6;
  long m0, n0;
  if (swzn) {
    int total = gridDim.x;
    int x = blockIdx.x & 7, jj = blockIdx.x >> 3;
    int q = total >> 3, rb = total & 7;
    int st = x * q + (x < rb ? x : rb);
    int s = st + jj;
    int rowt = s / swzn;
    m0 = (long)rowt * 128;
    n0 = (long)(s - rowt * swzn) * 128;
  } else {
    m0 = (long)blockIdx.x * 128;
    n0 = (long)blockIdx.y * 128;
  }
  int ks, kend;
  long chead = 0;
  int hz = 0;
  if (hA | hB | hC) {
    int z = blockIdx.z;
    hz = z / nsplit;
    int sp = z - hz * nsplit;
    A += (long)hz * hA;
    B += (long)hz * hB;
    chead = (MODE == M_PART) ? (long)z * hC : (long)hz * hC;
    ks = sp * kper;
    kend = ks + kper; if (kend > Ksteps) kend = Ksteps;
  } else {
    ks = blockIdx.z * kper;
    kend = ks + kper; if (kend > Ksteps) kend = Ksteps;
  }
  if (MODE == M_BLEND) ein += (long)hz * hE;

  const u16 *ag[2], *bg[2];
  u16 *al[2], *bl[2];
#pragma unroll
  for (int i = 0; i < 2; ++i) {
    int s = (wid * 2 + i) * 64 + lane;
    int row = s >> 2, cs = (s & 3) ^ ((row >> 1) & 3);
    ag[i] = A + (m0 + row) * (long)lda + cs * 8;
    bg[i] = B + (n0 + row) * (long)ldb + cs * 8;
    al[i] = As + (wid * 2 + i) * 512;
    bl[i] = Bs + (wid * 2 + i) * 512;
  }
  const int kq = lane >> 4, rr = lane & 15;
  const int wm = wid >> 1, wn = wid & 1;

  f32x4 acc[4][4] = {};

  for (; ks < kend; ++ks) {
    long ko = (long)ks * 32;
#pragma unroll
    for (int i = 0; i < 2; ++i) {
      __builtin_amdgcn_global_load_lds((const __attribute__((address_space(1))) unsigned int*)(ag[i] + ko),
                                       (__attribute__((address_space(3))) unsigned int*)al[i], 16, 0, 0);
      __builtin_amdgcn_global_load_lds((const __attribute__((address_space(1))) unsigned int*)(bg[i] + ko),
                                       (__attribute__((address_space(3))) unsigned int*)bl[i], 16, 0, 0);
    }
    __syncthreads();
    bf16x8 af[4], bff[4];
#pragma unroll
    for (int i = 0; i < 4; ++i) {
      int ra = wm * 64 + i * 16 + rr, ca = kq ^ ((ra >> 1) & 3);
      af[i] = *(const bf16x8*)(As + ra * 32 + ca * 8);
      int rb = wn * 64 + i * 16 + rr, cb = kq ^ ((rb >> 1) & 3);
      bff[i] = *(const bf16x8*)(Bs + rb * 32 + cb * 8);
    }
#pragma unroll
    for (int i = 0; i < 4; ++i)
#pragma unroll
      for (int j = 0; j < 4; ++j)
        acc[i][j] = __builtin_amdgcn_mfma_f32_16x16x32_bf16(af[i], bff[j], acc[i][j], 0, 0, 0);
    __syncthreads();
  }

  float* Cf = (float*)C1v;
  u16* Cu = (u16*)C1v;
  const int r4 = (lane >> 4) << 2;
#pragma unroll
  for (int i = 0; i < 4; ++i) {
#pragma unroll
    for (int rg = 0; rg < 4; ++rg) {
      long row = m0 + wm * 64 + i * 16 + r4 + rg;
      if (row >= M) continue;
      float scale = 0.f, al_ = 0.f, ml_ = 0.f;
      if (MODE == M_SCALE2) scale = 1.f / (rowsum[(long)hz * M + row] + 1e-5f);
      if (MODE == M_BLEND) { al_ = *alphap; ml_ = 1.f - al_; }
#pragma unroll
      for (int j = 0; j < 4; ++j) {
        long col = n0 + wn * 64 + j * 16 + rr;
        float v = acc[i][j][rg];
        long idx = chead + row * (long)ldc + col;
        if (MODE == M_ATOMIC) atomicAdd(Cf + idx, v);
        else if (MODE == M_PART) Cf[idx] = v;
        else if (MODE == M_SCALE2) { float sv = v * scale; Cf[idx] = sv; C2[idx] = sv; }
        else if (MODE == M_BLEND) { float e = ein[row * (long)ldein + col]; Cf[idx] = fmaxf(al_ * v + ml_ * e, 0.f); }
        else if (MODE == M_BF16) Cu[idx] = f2bf(v);
        else if (MODE == M_BF16B) Cu[idx] = f2bf(v + bias[col]);
        else if (MODE == M_F32B) Cf[idx] = v + bias[col];
      }
    }
  }
}

// ---------------- converters ----------------
__global__ void k_cvt(const float* __restrict__ in, u16* __restrict__ out, long R, long C, long Cp, long ostride)
{
  long idx = (long)blockIdx.x * blockDim.x + threadIdx.x;
  long cw = Cp >> 3;
  if (idx >= R * cw) return;
  long r = idx / cw, c8 = (idx % cw) << 3;
  u16 tmp[8];
  if (c8 < C) {
    const f32x4* p = (const f32x4*)(in + r * C + c8);
    f32x4 a = p[0], b = p[1];
#pragma unroll
    for (int i = 0; i < 4; ++i) { tmp[i] = f2bf(a[i]); tmp[4 + i] = f2bf(b[i]); }
  } else {
#pragma unroll
    for (int i = 0; i < 8; ++i) tmp[i] = 0;
  }
  uint4 w_; __builtin_memcpy(&w_, tmp, 16);
  *(uint4*)(out + r * ostride + c8) = w_;
}

__global__ __launch_bounds__(256) void k_cvtT(const float* __restrict__ in, u16* __restrict__ out,
                                              int Bh, int R, int C, int Rp)
{
  __shared__ float tile[64][65];
  int bid = blockIdx.x;
  int nrt = Rp >> 6;
  int rt = bid % nrt; bid /= nrt;
  int nct = C >> 6;
  int ct = bid % nct; int b = bid / nct;
  int t = threadIdx.x;
  int tr = t >> 4, tc4 = (t & 15) << 2;
#pragma unroll
  for (int i = 0; i < 4; ++i) {
    int r = (rt << 6) + tr + i * 16;
    f32x4 v = {0.f, 0.f, 0.f, 0.f};
    if (r < R) v = *(const f32x4*)(in + ((long)b * R + r) * C + (ct << 6) + tc4);
    tile[tr + i * 16][tc4 + 0] = v[0];
    tile[tr + i * 16][tc4 + 1] = v[1];
    tile[tr + i * 16][tc4 + 2] = v[2];
    tile[tr + i * 16][tc4 + 3] = v[3];
  }
  __syncthreads();
  int wc = t >> 4, wr4 = (t & 15) << 2;
#pragma unroll
  for (int i = 0; i < 4; ++i) {
    int c = wc + i * 16;
    u16 o[4];
#pragma unroll
    for (int k2 = 0; k2 < 4; ++k2) o[k2] = f2bf(tile[wr4 + k2][c]);
    unsigned long long pk; __builtin_memcpy(&pk, o, 8);
    *(unsigned long long*)(out + ((long)b * C + (ct << 6) + c) * Rp + (rt << 6) + wr4) = pk;
  }
}

// 4 adjacency planes: f32 [N][C] -> bf16 planes + per-plane rowsum
__global__ __launch_bounds__(256) void k_adj4(const float* __restrict__ a0, const float* __restrict__ a1,
                                              const float* __restrict__ a2, const float* __restrict__ a3,
                                              u16* __restrict__ o01, u16* __restrict__ o23,
                                              float* __restrict__ rowsum, int C, int Cp, int N)
{
  int r = blockIdx.x, pl = blockIdx.y, t = threadIdx.x;
  const float* in = pl == 0 ? a0 : pl == 1 ? a1 : pl == 2 ? a2 : a3;
  u16* out = pl < 2 ? o01 + (size_t)pl * N * Cp : o23 + (size_t)(pl - 2) * N * Cp;
  f32x4 v = {0.f, 0.f, 0.f, 0.f};
  int c = t << 2;
  if (c + 3 < C) v = *(const f32x4*)(in + (long)r * C + c);
  u16 o[4];
#pragma unroll
  for (int i = 0; i < 4; ++i) o[i] = f2bf(v[i]);
  unsigned long long pk; __builtin_memcpy(&pk, o, 8);
  *(unsigned long long*)(out + (long)r * Cp + c) = pk;
  float s = wred_sum(v[0] + v[1] + v[2] + v[3]);
  __shared__ float ws4[4];
  if ((t & 63) == 0) ws4[t >> 6] = s;
  __syncthreads();
  if (t == 0) rowsum[(long)pl * N + r] = ws4[0] + ws4[1] + ws4[2] + ws4[3];
}

// reduce NS partial planes: o[h][i] = sum_sp P[h*NS+sp][i], plane = 32768 f32
__global__ void k_red(const float* __restrict__ P, float* __restrict__ o, int NS)
{
  int i = blockIdx.x * 256 + threadIdx.x;         // 0..65535
  int h = i >> 15, rem = i & 32767;
  const float* p = P + (long)h * NS * 32768 + rem;
  float s = 0.f;
  for (int k = 0; k < NS; ++k) s += p[(long)k * 32768];
  o[i] = s;
}

// ---------------- CSR build ----------------
__global__ void k_zero_i(int* p, int n) { for (int i = blockIdx.x * blockDim.x + threadIdx.x; i < n; i += gridDim.x * blockDim.x) p[i] = 0; }
__global__ void k_copy_i(const int* __restrict__ a, int* __restrict__ b, int n) { for (int i = blockIdx.x * blockDim.x + threadIdx.x; i < n; i += gridDim.x * blockDim.x) b[i] = a[i]; }
__global__ void k_hist(const int* __restrict__ dst, int* __restrict__ deg, int E)
{ for (int i = blockIdx.x * blockDim.x + threadIdx.x; i < E; i += gridDim.x * blockDim.x) atomicAdd(&deg[dst[i]], 1); }
__global__ void k_scatter(const int* __restrict__ src, const int* __restrict__ dst, int* __restrict__ cur,
                          int* __restrict__ srcs, int E)
{
  for (int i = blockIdx.x * blockDim.x + threadIdx.x; i < E; i += gridDim.x * blockDim.x) {
    int p = atomicAdd(&cur[dst[i]], 1);
    srcs[p] = src[i];
  }
}
// single-block scan: per-thread serial chunk + LDS scan + serial writeback
__global__ __launch_bounds__(1024) void k_scan(const int* __restrict__ deg, int* __restrict__ off, int n)
{
  __shared__ int bsum[1024];
  int t = threadIdx.x;
  int per = (n + 1023) >> 10;
  int s0 = t * per, s1 = s0 + per; if (s1 > n) s1 = n;
  int s = 0;
  for (int i = s0; i < s1; ++i) s += deg[i];
  bsum[t] = s;
  __syncthreads();
  for (int d = 1; d < 1024; d <<= 1) {
    int x = (t >= d) ? bsum[t - d] : 0;
    __syncthreads();
    bsum[t] += x;
    __syncthreads();
  }
  if (t == 0) off[0] = 0;
  int run = t ? bsum[t - 1] : 0;
  for (int i = s0; i < s1; ++i) { run += deg[i]; off[i + 1] = run; }
}

// ---------------- GAT ----------------
// es/ed dots + fused int8 row quantization; q8 layout is DIM-MAJOR: row byte = d*4 + hd
__global__ __launch_bounds__(256) void k_esed(const u16* __restrict__ h, const float* __restrict__ as_,
                                              const float* __restrict__ ad_, float* __restrict__ esq,
                                              float* __restrict__ ed, signed char* __restrict__ q8, int N)
{
  __shared__ int stg[4][64];
  int n = blockIdx.x, t = threadIdx.x, hd = t >> 6, l = t & 63;
  long base = (long)n * 1024 + hd * 256 + (l << 2);
  ushort4 hv = *(const ushort4*)(h + base);
  float h0 = bf2f(hv.x), h1 = bf2f(hv.y), h2 = bf2f(hv.z), h3 = bf2f(hv.w);
  const float* ap = as_ + hd * 256 + (l << 2);
  const float* dp = ad_ + hd * 256 + (l << 2);
  float ps = h0 * ap[0] + h1 * ap[1] + h2 * ap[2] + h3 * ap[3];
  float pd = h0 * dp[0] + h1 * dp[1] + h2 * dp[2] + h3 * dp[3];
  ps = wred_sum(ps); pd = wred_sum(pd);
  float amax = fmaxf(fmaxf(fabsf(h0), fabsf(h1)), fmaxf(fabsf(h2), fabsf(h3)));
  amax = wred_max(amax);
  float rsc = amax > 0.f ? 127.f / amax : 0.f;
  signed char qb[4];
  qb[0] = (signed char)__float2int_rn(h0 * rsc);
  qb[1] = (signed char)__float2int_rn(h1 * rsc);
  qb[2] = (signed char)__float2int_rn(h2 * rsc);
  qb[3] = (signed char)__float2int_rn(h3 * rsc);
  int qw; __builtin_memcpy(&qw, qb, 4);
  stg[hd][l] = qw;
  if (l == 0) {
    esq[n * 8 + hd] = ps;
    esq[n * 8 + 4 + hd] = amax * (1.f / 127.f);
    ed[n * 4 + hd] = pd;
  }
  __syncthreads();
  if (t < 64) {
    int b0 = stg[0][t], b1 = stg[1][t], b2 = stg[2][t], b3 = stg[3][t];
    unsigned r[4];
#pragma unroll
    for (int i = 0; i < 4; ++i) {
      int sh = 8 * i;
      r[i] = ((unsigned)((b0 >> sh) & 0xff)) | ((unsigned)((b1 >> sh) & 0xff) << 8) |
             ((unsigned)((b2 >> sh) & 0xff) << 16) | ((unsigned)((b3 >> sh) & 0xff) << 24);
    }
    uint4 o; __builtin_memcpy(&o, r, 16);
    *(uint4*)(q8 + (long)n * 1024 + (t << 4)) = o;
  }
}

// persistent wave-per-node softmax aggregation; dim-major int8 gather;
// LDS broadcast of (weights, src). grid (1024, 2 sides), wave-strided node loop.
__global__ __launch_bounds__(256) void k_gat(const signed char* __restrict__ q8,
                                             const float* __restrict__ esq, const float* __restrict__ ed,
                                             const int* __restrict__ off0, const int* __restrict__ srcs0,
                                             const int* __restrict__ off1, const int* __restrict__ srcs1,
                                             u16* __restrict__ x0, u16* __restrict__ x1, int N, int NPq)
{
  __shared__ f32x4 sw[4][64];
  __shared__ int ss[4][64];
  int t = threadIdx.x, w = t >> 6, l = t & 63;
  int side = blockIdx.y;
  const int* off = side ? off1 : off0;
  const int* srcs = side ? srcs1 : srcs0;
  u16* xout = side ? x1 : x0;
  size_t ofs = side ? (size_t)NPq : 0;
  q8 += ofs * 1024; esq += ofs * 8;
  const long loff = l << 2;
  const int nstride = gridDim.x * 4;

  for (int n = blockIdx.x * 4 + w; n < N; n += nstride) {
    int e0 = off[n], deg = off[n + 1] - e0;
    f32x4 edv = *(const f32x4*)(ed + (ofs + n) * 4);

    f32x4 m = {-1e30f, -1e30f, -1e30f, -1e30f};
    f32x4 psum = {0.f, 0.f, 0.f, 0.f};
    f32x4 acc0 = {0.f, 0.f, 0.f, 0.f};
    f32x4 acc1 = {0.f, 0.f, 0.f, 0.f};
    f32x4 acc2 = {0.f, 0.f, 0.f, 0.f};
    f32x4 acc3 = {0.f, 0.f, 0.f, 0.f};

    for (int base = 0; base < deg; base += 64) {
      int cnt = min(64, deg - base);
      bool act = l < cnt;
      int s = 0;
      f32x4 v = {-1e30f, -1e30f, -1e30f, -1e30f};
      if (act) {
        s = srcs[e0 + base + l];
        f32x4 es4 = *(const f32x4*)(esq + (long)s * 8);
#pragma unroll
        for (int hd = 0; hd < 4; ++hd) {
          float x = es4[hd] + edv[hd];
          v[hd] = x >= 0.f ? x : 0.2f * x;
        }
      }
      f32x4 mc = v;
      wred_max4(mc);
      f32x4 nm;
#pragma unroll
      for (int hd = 0; hd < 4; ++hd) nm[hd] = fmaxf(m[hd], mc[hd]);
      f32x4 sc;
#pragma unroll
      for (int hd = 0; hd < 4; ++hd) sc[hd] = __expf(m[hd] - nm[hd]);
      psum *= sc;
      acc0 *= sc[0]; acc1 *= sc[1]; acc2 *= sc[2]; acc3 *= sc[3];
      m = nm;
      f32x4 wq4 = {0.f, 0.f, 0.f, 0.f};
      if (act) {
        f32x4 qs4 = *(const f32x4*)(esq + (long)s * 8 + 4);
#pragma unroll
        for (int hd = 0; hd < 4; ++hd) {
          float e = __expf(v[hd] - m[hd]);
          psum[hd] += e;
          wq4[hd] = e * qs4[hd];
        }
      }
      sw[w][l] = wq4;
      ss[w][l] = s;
#pragma unroll 4
      for (int j = 0; j < cnt; ++j) {
        f32x4 w4 = sw[w][j];
        int sj = ss[w][j];
        uint4 c = *(const uint4*)(q8 + (long)sj * 1024 + (l << 4));
        const int* cw = (const int*)&c;
#pragma unroll
        for (int i = 0; i < 4; ++i) {
          int ci = cw[i];
          acc0[i] += w4[0] * (float)((signed char)(ci));
          acc1[i] += w4[1] * (float)((signed char)(ci >> 8));
          acc2[i] += w4[2] * (float)((signed char)(ci >> 16));
          acc3[i] += w4[3] * (float)(ci >> 24);
        }
      }
    }
    wred_sum4(psum);
    f32x4 rd;
#pragma unroll
    for (int hd = 0; hd < 4; ++hd) rd[hd] = 1.f / (psum[hd] + 1e-16f);
    float mean[4]; float nrm = 0.f;
#pragma unroll
    for (int i = 0; i < 4; ++i) {
      float y0 = acc0[i] * rd[0]; y0 = y0 > 0.f ? y0 : __expf(y0) - 1.f;
      float y1 = acc1[i] * rd[1]; y1 = y1 > 0.f ? y1 : __expf(y1) - 1.f;
      float y2 = acc2[i] * rd[2]; y2 = y2 > 0.f ? y2 : __expf(y2) - 1.f;
      float y3 = acc3[i] * rd[3]; y3 = y3 > 0.f ? y3 : __expf(y3) - 1.f;
      float mv = 0.25f * (y0 + y1 + y2 + y3);
      mean[i] = mv; nrm += mv * mv;
    }
    nrm = wred_sum(nrm);
    float scn = 1.f / fmaxf(sqrtf(nrm), 1e-12f);
    u16 o[4];
#pragma unroll
    for (int i = 0; i < 4; ++i) o[i] = f2bf(mean[i] * scn);
    unsigned long long pk; __builtin_memcpy(&pk, o, 8);
    *(unsigned long long*)(xout + (long)n * 768 + loff) = pk;
  }
}

// ---------------- MHA (folded) ----------------
__global__ void k_bias2(const float* __restrict__ wq, const float* __restrict__ wk,
                        const float* __restrict__ fcw,
                        const float* __restrict__ bq, const float* __restrict__ bk,
                        const float* __restrict__ bv,
                        float* __restrict__ vq1, float* __restrict__ vq2,
                        float* __restrict__ beff2, float* __restrict__ s3)
{
  int t = blockIdx.x * 256 + threadIdx.x;   // 0..1023
  int h = t >> 8, d = t & 255;
  float a1 = 0.f, a2 = 0.f, a3 = 0.f;
  for (int j = 0; j < 256; ++j) {
    a1 += wk[(long)d * 1024 + h * 256 + j] * bq[h * 256 + j];
    a2 += wq[(long)d * 1024 + h * 256 + j] * bk[h * 256 + j];
    a3 += bv[h * 256 + j] * fcw[(long)(h * 256 + j) * 256 + d];
  }
  vq1[t] = a1; vq2[t] = a2; beff2[t] = a3;
  if (d == 0) {
    float s = 0.f;
    for (int j = 0; j < 256; ++j) s += bq[h * 256 + j] * bk[h * 256 + j];
    s3[h] = s;
  }
}

// per-node scores; grid (N, 2 sides)
__global__ __launch_bounds__(256) void k_score2(const u16* __restrict__ x, const u16* __restrict__ kg,
                                                const float* __restrict__ vq1, const float* __restrict__ vq2,
                                                const float* __restrict__ s3, float* __restrict__ attn,
                                                int N, int NPq)
{
  int n = blockIdx.x, side = blockIdx.y, t = threadIdx.x, hd = t >> 6, l = t & 63;
  long rbase = (long)side * 3 * NPq + (long)n * 3;
  int i4 = l << 2;
  f32x4 xr[3], kc[3];
#pragma unroll
  for (int r = 0; r < 3; ++r) {
    ushort4 a = *(const ushort4*)(x + (rbase + r) * 256 + i4);
    xr[r][0] = bf2f(a.x); xr[r][1] = bf2f(a.y); xr[r][2] = bf2f(a.z); xr[r][3] = bf2f(a.w);
    ushort4 b = *(const ushort4*)(kg + (rbase + r) * 1024 + hd * 256 + i4);
    kc[r][0] = bf2f(b.x); kc[r][1] = bf2f(b.y); kc[r][2] = bf2f(b.z); kc[r][3] = bf2f(b.w);
  }
  f32x4 v1 = *(const f32x4*)(vq1 + hd * 256 + i4);
  f32x4 v2 = *(const f32x4*)(vq2 + hd * 256 + i4);
  float red[15];
#pragma unroll
  for (int r = 0; r < 3; ++r)
#pragma unroll
    for (int c = 0; c < 3; ++c) {
      f32x4 p = xr[r] * kc[c];
      red[r * 3 + c] = p[0] + p[1] + p[2] + p[3];
    }
#pragma unroll
  for (int c = 0; c < 3; ++c) {
    f32x4 p1 = xr[c] * v1;
    f32x4 p2 = xr[c] * v2;
    red[9 + c] = p1[0] + p1[1] + p1[2] + p1[3];
    red[12 + c] = p2[0] + p2[1] + p2[2] + p2[3];
  }
#pragma unroll
  for (int i = 0; i < 15; ++i) red[i] = wred_sum(red[i]);
  if (l == 0) {
    float s3h = s3[hd];
    float* out = attn + ((long)side * N + n) * 36 + hd * 9;
#pragma unroll
    for (int r = 0; r < 3; ++r) {
      float v0 = (red[r * 3 + 0] + red[9 + 0] + red[12 + r] + s3h) * 0.0625f;
      float v1_ = (red[r * 3 + 1] + red[9 + 1] + red[12 + r] + s3h) * 0.0625f;
      float v2_ = (red[r * 3 + 2] + red[9 + 2] + red[12 + r] + s3h) * 0.0625f;
      float mm = fmaxf(v0, fmaxf(v1_, v2_));
      float e0 = __expf(v0 - mm), e1 = __expf(v1_ - mm), e2 = __expf(v2_ - mm);
      float rs = 1.f / (e0 + e1 + e2);
      out[r * 3 + 0] = e0 * rs; out[r * 3 + 1] = e1 * rs; out[r * 3 + 2] = e2 * rs;
    }
  }
}

// fused combine + fc-bias + residual + LayerNorm + range-mean; grid (N, 2 sides)
__global__ __launch_bounds__(256) void k_cln(const u16* __restrict__ vf, const float* __restrict__ attn,
                                             const u16* __restrict__ x, const float* __restrict__ fcb,
                                             const float* __restrict__ g, const float* __restrict__ b,
                                             float* __restrict__ out0, float* __restrict__ out1,
                                             int N, int NPq)
{
  int n = blockIdx.x, side = blockIdx.y, t = threadIdx.x, w = t >> 6, l = t & 63;
  long rbase = (long)side * 3 * NPq + (long)n * 3;
  float* out = (side ? out1 : out0) + (long)n * 768;
  __shared__ float aa[36];
  __shared__ float ybuf[3][256];
  if (t < 36) aa[t] = attn[((long)side * N + n) * 36 + t];
  __syncthreads();
  if (w < 3) {
    int d4 = l << 2;
    f32x4 acc = {0.f, 0.f, 0.f, 0.f};
#pragma unroll
    for (int h = 0; h < 4; ++h)
#pragma unroll
      for (int rp = 0; rp < 3; ++rp) {
        float wgt = aa[h * 9 + w * 3 + rp];
        ushort4 vv = *(const ushort4*)(vf + (rbase + rp) * 1024 + h * 256 + d4);
        acc[0] += wgt * bf2f(vv.x); acc[1] += wgt * bf2f(vv.y);
        acc[2] += wgt * bf2f(vv.z); acc[3] += wgt * bf2f(vv.w);
      }
    f32x4 fb = *(const f32x4*)(fcb + d4);
    ushort4 xu = *(const ushort4*)(x + (rbase + w) * 256 + d4);
    acc[0] += fb[0] + bf2f(xu.x); acc[1] += fb[1] + bf2f(xu.y);
    acc[2] += fb[2] + bf2f(xu.z); acc[3] += fb[3] + bf2f(xu.w);
    float s1 = acc[0] + acc[1] + acc[2] + acc[3];
    float s2 = acc[0] * acc[0] + acc[1] * acc[1] + acc[2] * acc[2] + acc[3] * acc[3];
    s1 = wred_sum(s1); s2 = wred_sum(s2);
    float mu = s1 * 0.00390625f;
    float var = s2 * 0.00390625f - mu * mu;
    float rs = rsqrtf(var + 1e-5f);
#pragma unroll
    for (int i = 0; i < 4; ++i) {
      int d = d4 + i;
      ybuf[w][d] = (acc[i] - mu) * rs * g[d] + b[d];
    }
  }
  __syncthreads();
  if (t < 64) {
#pragma unroll
    for (int i = 0; i < 4; ++i) {
      int d = (t << 2) + i;
      out[d] = (ybuf[0][d] + ybuf[1][d] + ybuf[2][d]) * (1.f / 3.f);
    }
  }
}

// aug = e + ent, both sides; out2/out3 contiguous
__global__ void k_aug(const float* __restrict__ e, const float* __restrict__ ent0,
                      const float* __restrict__ ent1, float* __restrict__ out, int N)
{
  long i = (long)blockIdx.x * blockDim.x + threadIdx.x;
  if (i >= (long)N * 128) return;
  int side = i >= (long)N * 64;
  long ii = side ? i - (long)N * 64 : i;
  const float* ent = side ? ent1 : ent0;
  long n = ii >> 6; int d4 = (int)(ii & 63) << 2;
  f32x4 a = *(const f32x4*)(e + ((long)side * N + n) * 256 + d4);
  f32x4 c = *(const f32x4*)(ent + n * 256 + d4);
  *(f32x4*)(out + ((long)side * N + n) * 768 + d4) = a + c;
}

// ---------------- host ----------------
extern "C" void kernel_launch(void* const* d_in, const int* in_sizes, int n_in,
                              void* d_out, int out_size, void* d_ws, size_t ws_size,
                              hipStream_t stream)
{
  (void)n_in; (void)out_size; (void)ws_size;
  const int N = 20000, NP = 20096, RNUM = 1000, RP = 1024;
  const int NT2 = NP + N;
  const int NS = 64;
  const int Es = in_sizes[26] / 2, Et = in_sizes[27] / 2;

  const float* ent_sr = (const float*)d_in[0];
  const float* ent_tg = (const float*)d_in[1];
  const float* rel_in[2] = {(const float*)d_in[2], (const float*)d_in[3]};
  const float* alphap = (const float*)d_in[4];
  const float* ums[2] = {(const float*)d_in[5], (const float*)d_in[7]};
  const float* vt[2]  = {(const float*)d_in[6], (const float*)d_in[8]};
  const float* adj[4] = {(const float*)d_in[9], (const float*)d_in[10], (const float*)d_in[11], (const float*)d_in[12]};
  const float* gat_W  = (const float*)d_in[13];
  const float* gat_as = (const float*)d_in[14];
  const float* gat_ad = (const float*)d_in[15];
  const float* wq = (const float*)d_in[16]; const float* bq = (const float*)d_in[17];
  const float* wk = (const float*)d_in[18]; const float* bk = (const float*)d_in[19];
  const float* wv = (const float*)d_in[20]; const float* bv = (const float*)d_in[21];
  const float* fcw = (const float*)d_in[22]; const float* fcb = (const float*)d_in[23];
  const float* lng = (const float*)d_in[24]; const float* lnb = (const float*)d_in[25];
  const int* edges[2] = {(const int*)d_in[26], (const int*)d_in[27]};
  const int Ecnt[2] = {Es, Et};

  float* out0 = (float*)d_out;
  float* out1 = out0 + (size_t)N * 768;
  float* out2 = out1 + (size_t)N * 768;
  float* out3 = out2 + (size_t)N * 768;

  char* wsp = (char*)d_ws; size_t wo = 0;
  auto alloc = [&](size_t bytes) { void* p = wsp + wo; wo = (wo + bytes + 255) & ~(size_t)255; return p; };

  u16* A_sr = (u16*)alloc((size_t)NP * 768 * 2);
  u16* A_tg = (u16*)alloc((size_t)NP * 768 * 2);     // contiguous after A_sr (size % 256 == 0)
  u16* QBUF = (u16*)alloc((size_t)3 * NT2 * 1024 * 2);  // 246 MB: rel adj 0/1, GAT h, vf
  u16* KBUF = (u16*)alloc((size_t)3 * NT2 * 1024 * 2);  // 246 MB: rel adj 2/3, SVD scratch, q8, kg
  float* PART = (float*)alloc((size_t)2 * NS * 32768 * 4);
  float* rowsum = (float*)alloc((size_t)4 * N * 4);
  u16* relT[2] = {(u16*)alloc(256 * RP * 2), (u16*)alloc(256 * RP * 2)};
  u16* WtG = (u16*)alloc((size_t)2 * 1024 * 256 * 2);
  u16* fcT = (u16*)alloc(256 * 1024 * 2);
  u16* wqB = (u16*)alloc(256 * 1024 * 2);
  u16* wkB = (u16*)alloc(256 * 1024 * 2);
  u16* wvB = (u16*)alloc(256 * 1024 * 2);
  u16* gT  = (u16*)alloc((size_t)4 * 256 * 256 * 2);
  u16* vfT = (u16*)alloc((size_t)4 * 256 * 256 * 2);
  float* vq1 = (float*)alloc(1024 * 4);
  float* vq2 = (float*)alloc(1024 * 4);
  float* beff2 = (float*)alloc(1024 * 4);
  float* s3b = (float*)alloc(4 * 4);
  float* esqb = (float*)alloc((size_t)NT2 * 8 * 4);
  float* edb = (float*)alloc((size_t)NT2 * 4 * 4);
  float* attn = (float*)alloc((size_t)2 * N * 36 * 4);
  int* off_[2]; int* cur_[2]; int* srcs_[2];
  for (int s = 0; s < 2; ++s) {
    off_[s] = (int*)alloc((size_t)(N + 4) * 4);
    cur_[s] = (int*)alloc((size_t)(N + 4) * 4);
    srcs_[s] = (int*)alloc((size_t)Ecnt[s] * 4);
  }
  float* tT2 = (float*)alloc((size_t)2 * 256 * 128 * 4);
  u16* tTb2 = (u16*)alloc((size_t)2 * 256 * 128 * 2);

  // aliases
  u16* hbuf = QBUF;                 // GAT phase
  u16* vfbuf = QBUF;                // MHA phase
  u16* adjbQ = QBUF;                // rel planes 0,1
  u16* adjbK = KBUF;                // rel planes 2,3
  float* e_b = (float*)KBUF;        // SVD: [2][N][256] f32
  u16* eT = (u16*)(e_b + (size_t)2 * N * 256);   // [2][256][NP]
  u16* vtb0 = eT + (size_t)2 * 256 * NP;         // [2][128][NP]
  u16* umb0 = vtb0 + (size_t)2 * 128 * NP;       // [2][NP][128] (rows 0..N used)
  signed char* q8buf = (signed char*)KBUF;       // GAT phase (dim-major int8)
  u16* kgbuf = KBUF;                             // MHA phase

  const float* ent_s[2] = {ent_sr, ent_tg};

  auto cvt = [&](const float* in, u16* out, long R, long C, long Cp, long ostr) {
    long total = R * (Cp >> 3);
    int blocks = (int)((total + 255) / 256);
    k_cvt<<<blocks, 256, 0, stream>>>(in, out, R, C, Cp, ostr);
  };
  auto cvtT = [&](const float* in, u16* out, int Bh, int R, int C, int Rp) {
    int blocks = (Rp >> 6) * (C >> 6) * Bh;
    k_cvtT<<<blocks, 256, 0, stream>>>(in, out, Bh, R, C, Rp);
  };
  auto gemm = [&](int mode, const u16* A, const u16* B, int M, int lda, int ldb, int Kp, int Nt,
                  int zdim, int nsplit,
                  void* C1, float* C2, int ldc, const float* rs, const float* ein, int ldein,
                  const float* alp, const float* bias,
                  long hA = 0, long hB = 0, long hC = 0, long hE = 0, int swz = 0) {
    int Ks = Kp >> 5;
    bool hmode = (hA | hB | hC) != 0;
    int kper = hmode ? (Ks + nsplit - 1) / nsplit
                     : (zdim > 1 ? (Ks + zdim - 1) / zdim : Ks);
    int nrt = (M + 127) >> 7;
    dim3 g(nrt, Nt, zdim);
    int swzn = 0;
    if (swz && !hmode && zdim == 1) { g = dim3(nrt * Nt, 1, 1); swzn = Nt; }
    switch (mode) {
      case M_ATOMIC: k_gemm<M_ATOMIC><<<g, 256, 0, stream>>>(A, B, M, lda, ldb, Ks, kper, C1, C2, ldc, rs, ein, ldein, alp, bias, hA, hB, hC, nsplit, hE, swzn); break;
      case M_SCALE2: k_gemm<M_SCALE2><<<g, 256, 0, stream>>>(A, B, M, lda, ldb, Ks, kper, C1, C2, ldc, rs, ein, ldein, alp, bias, hA, hB, hC, nsplit, hE, swzn); break;
      case M_BLEND:  k_gemm<M_BLEND><<<g, 256, 0, stream>>>(A, B, M, lda, ldb, Ks, kper, C1, C2, ldc, rs, ein, ldein, alp, bias, hA, hB, hC, nsplit, hE, swzn); break;
      case M_BF16:   k_gemm<M_BF16><<<g, 256, 0, stream>>>(A, B, M, lda, ldb, Ks, kper, C1, C2, ldc, rs, ein, ldein, alp, bias, hA, hB, hC, nsplit, hE, swzn); break;
      case M_BF16B:  k_gemm<M_BF16B><<<g, 256, 0, stream>>>(A, B, M, lda, ldb, Ks, kper, C1, C2, ldc, rs, ein, ldein, alp, bias, hA, hB, hC, nsplit, hE, swzn); break;
      case M_F32B:   k_gemm<M_F32B><<<g, 256, 0, stream>>>(A, B, M, lda, ldb, Ks, kper, C1, C2, ldc, rs, ein, ldein, alp, bias, hA, hB, hC, nsplit, hE, swzn); break;
      case M_PART:   k_gemm<M_PART><<<g, 256, 0, stream>>>(A, B, M, lda, ldb, Ks, kper, C1, C2, ldc, rs, ein, ldein, alp, bias, hA, hB, hC, nsplit, hE, swzn); break;
    }
  };

  // ---- CSR build (per side) ----
  for (int s = 0; s < 2; ++s) {
    k_zero_i<<<80, 256, 0, stream>>>(cur_[s], N);
    k_hist<<<1024, 256, 0, stream>>>(edges[s] + Ecnt[s], cur_[s], Ecnt[s]);
    k_scan<<<1, 1024, 0, stream>>>(cur_[s], off_[s], N);
    k_copy_i<<<80, 256, 0, stream>>>(off_[s], cur_[s], N);
    k_scatter<<<1024, 256, 0, stream>>>(edges[s], edges[s] + Ecnt[s], cur_[s], srcs_[s], Ecnt[s]);
  }

  // ---- Relation aggregator: one adj pass + two head-mode GEMMs ----
  cvtT(rel_in[0], relT[0], 1, RNUM, 256, RP);
  cvtT(rel_in[1], relT[1], 1, RNUM, 256, RP);
  {
    dim3 ga(N, 4);
    k_adj4<<<ga, 256, 0, stream>>>(adj[0], adj[1], adj[2], adj[3], adjbQ, adjbK, rowsum, RNUM, RP, N);
  }
  gemm(M_SCALE2, adjbQ, relT[0], N, RP, RP, RP, 2, 2, 1,
       out0 + 256, out2 + 256, 768, rowsum, nullptr, 0, nullptr, nullptr,
       (long)N * RP, 0, 256);
  gemm(M_SCALE2, adjbK, relT[1], N, RP, RP, RP, 2, 2, 1,
       out1 + 256, out3 + 256, 768, rowsum + 2 * N, nullptr, 0, nullptr, nullptr,
       (long)N * RP, 0, 256);

  // ---- SVD global-structure propagation (sides merged per layer) ----
  cvt(vt[0], vtb0, 128, N, NP, NP);
  cvt(vt[1], vtb0 + (size_t)128 * NP, 128, N, NP, NP);
  cvt(ums[0], umb0, N, 128, 128, 128);
  cvt(ums[1], umb0 + (size_t)NP * 128, N, 128, 128, 128);
  for (int l = 0; l < 2; ++l) {
    if (l == 0) {
      cvtT(ent_sr, eT, 1, N, 256, NP);
      cvtT(ent_tg, eT + (size_t)256 * NP, 1, N, 256, NP);
    } else {
      cvtT(e_b, eT, 2, N, 256, NP);
    }
    gemm(M_PART, eT, vtb0, 256, NP, NP, NP, 1, 2 * NS, NS,
         PART, nullptr, 128, nullptr, nullptr, 0, nullptr, nullptr,
         (long)256 * NP, (long)128 * NP, 32768);
    k_red<<<256, 256, 0, stream>>>(PART, tT2, NS);
    cvt(tT2, tTb2, 512, 128, 128, 128);
    if (l == 0) {
      for (int s = 0; s < 2; ++s)
        gemm(M_BLEND, umb0 + (size_t)s * NP * 128, tTb2 + (size_t)s * 32768, N, 128, 128, 128, 2, 1, 1,
             e_b + (size_t)s * N * 256, nullptr, 256, nullptr, ent_s[s], 256, alphap, nullptr,
             0, 0, 0, 0, 1);
    } else {
      gemm(M_BLEND, umb0, tTb2, N, 128, 128, 128, 2, 2, 1,
           e_b, nullptr, 256, nullptr, e_b, 256, alphap, nullptr,
           (long)NP * 128, 32768, (long)N * 256, (long)N * 256);
    }
  }
  k_aug<<<(int)(((long)N * 128 + 255) / 256), 256, 0, stream>>>(e_b, ent_sr, ent_tg, out2, N);

  // ---- GAT (2 layers, sides merged; dim-major int8 gather) ----
  cvt(ent_sr, A_sr, N, 256, 256, 768);
  cvt(ent_tg, A_tg, N, 256, 256, 768);
  cvtT(gat_W, WtG, 8, 256, 256, 256);
  for (int l = 0; l < 2; ++l) {
    gemm(M_BF16, A_sr + l * 256, WtG + (size_t)l * 1024 * 256, NT2, 768, 256, 256, 8, 1, 1,
         hbuf, nullptr, 1024, nullptr, nullptr, 0, nullptr, nullptr,
         0, 0, 0, 0, 1);
    k_esed<<<NT2, 256, 0, stream>>>(hbuf, gat_as + l * 1024, gat_ad + l * 1024, esqb, edb, q8buf, NT2);
    dim3 gg(1024, 2);
    k_gat<<<gg, 256, 0, stream>>>(q8buf, esqb, edb, off_[0], srcs_[0], off_[1], srcs_[1],
                                  A_sr + (l + 1) * 256, A_tg + (l + 1) * 256, N, NP);
  }

  // ---- MHA precompute ----
  cvt(wq, wqB, 256, 1024, 1024, 1024);
  cvt(wk, wkB, 256, 1024, 1024, 1024);
  cvt(wv, wvB, 256, 1024, 1024, 1024);
  cvtT(fcw, fcT, 1, 1024, 256, 1024);
  k_bias2<<<4, 256, 0, stream>>>(wq, wk, fcw, bq, bk, bv, vq1, vq2, beff2, s3b);
  gemm(M_BF16, wqB, wkB, 256, 1024, 1024, 256, 2, 4, 1, gT, nullptr, 256,
       nullptr, nullptr, 0, nullptr, nullptr, 256, 256, 65536);
  gemm(M_BF16, fcT, wvB, 256, 1024, 1024, 256, 2, 4, 1, vfT, nullptr, 256,
       nullptr, nullptr, 0, nullptr, nullptr, 256, 256, 65536);

  // ---- MHA over ranges + LN + mean (folded, sides merged) ----
  gemm(M_BF16, A_sr, gT, 3 * NT2, 256, 256, 256, 8, 1, 1, kgbuf, nullptr, 1024,
       nullptr, nullptr, 0, nullptr, nullptr, 0, 0, 0, 0, 1);
  {
    dim3 gs(N, 2);
    k_score2<<<gs, 256, 0, stream>>>(A_sr, kgbuf, vq1, vq2, s3b, attn, N, NP);
  }
  gemm(M_BF16B, A_sr, vfT, 3 * NT2, 256, 256, 256, 8, 1, 1, vfbuf, nullptr, 1024,
       nullptr, nullptr, 0, nullptr, beff2, 0, 0, 0, 0, 1);
  {
    dim3 gc(N, 2);
    k_cln<<<gc, 256, 0, stream>>>(vfbuf, attn, A_sr, fcb, lng, lnb, out0, out1, N, NP);
  }
}